// Round 13
// baseline (6166.050 us; speedup 1.0000x reference)
//
#include <hip/hip_runtime.h>

#define B_ 16
#define T_ 256
#define E_ 512
#define H_ 1024
#define V_ 32000

typedef float f32x4 __attribute__((ext_vector_type(4)));
typedef short short8 __attribute__((ext_vector_type(8)));

typedef __attribute__((address_space(1))) const void gas_t;
typedef __attribute__((address_space(3))) void las_t;

__device__ __forceinline__ unsigned short f2bf(float x) {
    unsigned int u = __float_as_uint(x);
    u += 0x7FFF + ((u >> 16) & 1);            // RTNE
    return (unsigned short)(u >> 16);
}
__device__ __forceinline__ float bf2f(unsigned short b) {
    return __uint_as_float(((unsigned int)b) << 16);
}
// fast gates: v_exp + fast-div; saturation-safe, ~2e-7 error
__device__ __forceinline__ float fsig(float x) {
    return __fdividef(1.f, 1.f + __expf(-x));
}
__device__ __forceinline__ float ftanh(float x) {
    float xc = fminf(fmaxf(x, -15.f), 15.f);
    float e  = __expf(-2.f * xc);
    return __fdividef(1.f - e, 1.f + e);
}

// ---------------------------------------------------------------------------
// Embedding gather fused with bf16 hi/lo split: emb[tokens] -> Ah/Al [4096,512]
// ---------------------------------------------------------------------------
__global__ __launch_bounds__(256)
void gather_cvt_k(const int* __restrict__ tokens, const float* __restrict__ emb,
                  unsigned short* __restrict__ Ah, unsigned short* __restrict__ Al)
{
    int i  = blockIdx.x * 256 + threadIdx.x;   // float4 id; 4096*128 total
    int bt = i >> 7;
    int e4 = i & 127;
    float4 v = ((const float4*)(emb + (size_t)tokens[bt] * E_))[e4];
    ushort4 h, l;
    h.x = f2bf(v.x); l.x = f2bf(v.x - bf2f(h.x));
    h.y = f2bf(v.y); l.y = f2bf(v.y - bf2f(h.y));
    h.z = f2bf(v.z); l.z = f2bf(v.z - bf2f(h.z));
    h.w = f2bf(v.w); l.w = f2bf(v.w - bf2f(h.w));
    ((ushort4*)Ah)[i] = h;
    ((ushort4*)Al)[i] = l;
}

// ---------------------------------------------------------------------------
// fp32 -> bf16 hi/lo split (A activations, row-major, no transpose)
// ---------------------------------------------------------------------------
__global__ __launch_bounds__(256)
void cvt_k(const float* __restrict__ A, unsigned short* __restrict__ Ah,
           unsigned short* __restrict__ Al)
{
    int i = blockIdx.x * 256 + threadIdx.x;    // float4 id
    float4 v = ((const float4*)A)[i];
    ushort4 h, l;
    h.x = f2bf(v.x); l.x = f2bf(v.x - bf2f(h.x));
    h.y = f2bf(v.y); l.y = f2bf(v.y - bf2f(h.y));
    h.z = f2bf(v.z); l.z = f2bf(v.z - bf2f(h.z));
    h.w = f2bf(v.w); l.w = f2bf(v.w - bf2f(h.w));
    ((ushort4*)Ah)[i] = h;
    ((ushort4*)Al)[i] = l;
}

// ---------------------------------------------------------------------------
// Weight transpose + split: W fp32 [K][Nfull], col slice [n0, n0+NS) ->
// Bh/Bl bf16 [NS][K]. 32x32 LDS tiles, +1 pad, coalesced both sides.
// ---------------------------------------------------------------------------
__global__ __launch_bounds__(256)
void twz_k(const float* __restrict__ W, unsigned short* __restrict__ Bh,
           unsigned short* __restrict__ Bl, int Kd, int Nfull, int n0)
{
    __shared__ float tile[32][33];
    int t  = threadIdx.x;
    int tx = t & 31, ty = t >> 5;              // ty 0..7
    int nb = blockIdx.x * 32, kb = blockIdx.y * 32;
    #pragma unroll
    for (int i = 0; i < 4; ++i)
        tile[ty + i * 8][tx] = W[(size_t)(kb + ty + i * 8) * Nfull + n0 + nb + tx];
    __syncthreads();
    #pragma unroll
    for (int i = 0; i < 4; ++i) {
        float v = tile[tx][ty + i * 8];
        unsigned short h = f2bf(v), l = f2bf(v - bf2f(h));
        size_t o = (size_t)(nb + ty + i * 8) * Kd + kb + tx;
        Bh[o] = h; Bl[o] = l;
    }
}

// ---------------------------------------------------------------------------
// Split-bf16 3-pass MFMA GEMM (round-5-verified core) + bijective XCD swizzle.
// ---------------------------------------------------------------------------
template<int DO_MASK>
__global__ __launch_bounds__(256)
void mgemm_k(const unsigned short* __restrict__ Ah, const unsigned short* __restrict__ Al,
             const unsigned short* __restrict__ Bh, const unsigned short* __restrict__ Bl,
             const float* __restrict__ bias, float* __restrict__ C,
             const int* __restrict__ tokens, int K, int ldc, int n0)
{
    __shared__ unsigned short LDSS[4][128 * 64];   // 64 KB: Ah,Al,Bh,Bl planes

    const int tid  = threadIdx.x;
    const int nwg = gridDim.x * gridDim.y;
    int lin = blockIdx.y * gridDim.x + blockIdx.x;
    lin = (lin & 7) * (nwg >> 3) + (lin >> 3);
    const int bm   = (lin / gridDim.x) * 128;
    const int bn   = (lin % gridDim.x) * 128;
    const int w    = tid >> 6, lane = tid & 63;
    const int wm   = (w >> 1) * 64, wn = (w & 1) * 64;
    const int l15  = lane & 15, lhi = lane >> 4;

    const unsigned short* gp = (w == 0) ? Ah : (w == 1) ? Al : (w == 2) ? Bh : Bl;
    const int rb = (w < 2) ? bm : bn;
    const int srow = lane >> 3;
    const int scol = (lane & 7) ^ srow;
    unsigned short* lbase = &LDSS[w][0];

    f32x4 acc[4][4];
    #pragma unroll
    for (int mi = 0; mi < 4; ++mi)
        #pragma unroll
        for (int ni = 0; ni < 4; ++ni) {
            f32x4 z = {0.f, 0.f, 0.f, 0.f};
            acc[mi][ni] = z;
        }

    for (int kt = 0; kt < K; kt += 64) {
        #pragma unroll
        for (int c = 0; c < 16; ++c) {
            const unsigned short* src =
                gp + (size_t)(rb + c * 8 + srow) * K + kt + scol * 8;
            __builtin_amdgcn_global_load_lds((gas_t*)src,
                                             (las_t*)(lbase + c * 512), 16, 0, 0);
        }
        __syncthreads();
        #pragma unroll
        for (int ks = 0; ks < 2; ++ks) {
            short8 ah[4], al[4], bh[4], bl[4];
            const int s = ks * 4 + lhi;
            #pragma unroll
            for (int mi = 0; mi < 4; ++mi) {
                int m = wm + mi * 16 + l15;
                int off = m * 64 + ((s ^ (m & 7)) * 8);
                ah[mi] = *(const short8*)(&LDSS[0][off]);
                al[mi] = *(const short8*)(&LDSS[1][off]);
            }
            #pragma unroll
            for (int ni = 0; ni < 4; ++ni) {
                int n = wn + ni * 16 + l15;
                int off = n * 64 + ((s ^ (n & 7)) * 8);
                bh[ni] = *(const short8*)(&LDSS[2][off]);
                bl[ni] = *(const short8*)(&LDSS[3][off]);
            }
            #pragma unroll
            for (int mi = 0; mi < 4; ++mi)
                #pragma unroll
                for (int ni = 0; ni < 4; ++ni) {
                    acc[mi][ni] = __builtin_amdgcn_mfma_f32_16x16x32_bf16(
                        ah[mi], bh[ni], acc[mi][ni], 0, 0, 0);
                    acc[mi][ni] = __builtin_amdgcn_mfma_f32_16x16x32_bf16(
                        ah[mi], bl[ni], acc[mi][ni], 0, 0, 0);
                    acc[mi][ni] = __builtin_amdgcn_mfma_f32_16x16x32_bf16(
                        al[mi], bh[ni], acc[mi][ni], 0, 0, 0);
                }
        }
        __syncthreads();
    }

    #pragma unroll
    for (int mi = 0; mi < 4; ++mi) {
        #pragma unroll
        for (int r = 0; r < 4; ++r) {
            int row = bm + wm + mi * 16 + lhi * 4 + r;
            bool msk = true;
            if (DO_MASK) msk = (tokens[row] != 0);
            #pragma unroll
            for (int ni = 0; ni < 4; ++ni) {
                int col = bn + wn + ni * 16 + l15;
                float v = acc[mi][ni][r] + bias[n0 + col];
                if (DO_MASK && !msk) v = ((n0 + col) == 0) ? 1.f : 0.f;
                C[(size_t)row * ldc + n0 + col] = v;
            }
        }
    }
}

// ---------------------------------------------------------------------------
// Wh [1024][4096] fp32 -> register-fragment image WhF (bf16 hi/lo B-frags).
// Also resets the 128 flag words (flagsA[64] + flagsB[64]).
// ---------------------------------------------------------------------------
__global__ __launch_bounds__(256)
void wprep_k(const float* __restrict__ Wh, uint4* __restrict__ WhF,
             unsigned* __restrict__ flags)
{
    int flat = blockIdx.x * 256 + threadIdx.x;      // 0 .. 524287
    if (flat < 128) flags[flat] = 0;
    int l  = flat & 63;
    int kf = (flat >> 6) & 3;
    int ct = (flat >> 8) & 3;
    int w  = (flat >> 10) & 7;
    int bx = flat >> 13;                            // 0..63
    int k0  = w * 128 + kf * 32 + 8 * (l >> 4);
    int col = ct * H_ + bx * 16 + (l & 15);
    unsigned short hi[8], lo[8];
    #pragma unroll
    for (int j = 0; j < 8; ++j) {
        float v = Wh[(size_t)(k0 + j) * (4 * H_) + col];
        hi[j] = f2bf(v); lo[j] = f2bf(v - bf2f(hi[j]));
    }
    size_t base = ((((size_t)bx * 8 + w) * 4 + ct) * 4 + kf) * 2;
    WhF[(base + 0) * 64 + l] = *(uint4*)hi;
    WhF[(base + 1) * 64 + l] = *(uint4*)lo;
}

// ---------------------------------------------------------------------------
// Persistent MFMA LSTM layer, round-13: TWO-CHAIN SOFTWARE PIPELINE.
// Batches 0-7 (chain A, gate lanes lhi<2) and 8-15 (chain B, lanes lhi>=2)
// are independent recurrences sharing Wh. They run half-a-step apart so each
// chain's MALL RTTs hide under the other's work; the two vmcnt(0) drains
// each pair {one chain's h-loads || other chain's h-stores}. MFMA runs with
// 8 valid rows per chain (other chain's columns are stale-but-finite, their
// C rows are ignored). Separate flags per chain; single-wave-0 polls.
// Tokens staged TRANSPOSED in LDS (tokT[t][b] -> conflict-free reads).
// ---------------------------------------------------------------------------
#define MFMA_SCATTER(RS)                                                      \
    do {                                                                      \
        f32x4 a0 = {0.f,0.f,0.f,0.f}, a1 = a0, a2 = a0, a3 = a0;              \
        _Pragma("unroll")                                                     \
        for (int kf = 0; kf < 4; ++kf) {                                      \
            unsigned short hh[8], hl[8];                                      \
            _Pragma("unroll")                                                 \
            for (int j = 0; j < 8; ++j) {                                     \
                unsigned d = hd[kf][j];                                       \
                hh[j] = (unsigned short)(d >> 16);                            \
                hl[j] = (unsigned short)(d & 0xFFFFu);                        \
            }                                                                 \
            short8 ah = *(short8*)hh, al = *(short8*)hl;                      \
            a0 = __builtin_amdgcn_mfma_f32_16x16x32_bf16(ah, Bhi[0][kf], a0, 0,0,0); \
            a0 = __builtin_amdgcn_mfma_f32_16x16x32_bf16(ah, Blo[0][kf], a0, 0,0,0); \
            a0 = __builtin_amdgcn_mfma_f32_16x16x32_bf16(al, Bhi[0][kf], a0, 0,0,0); \
            a1 = __builtin_amdgcn_mfma_f32_16x16x32_bf16(ah, Bhi[1][kf], a1, 0,0,0); \
            a1 = __builtin_amdgcn_mfma_f32_16x16x32_bf16(ah, Blo[1][kf], a1, 0,0,0); \
            a1 = __builtin_amdgcn_mfma_f32_16x16x32_bf16(al, Bhi[1][kf], a1, 0,0,0); \
            a2 = __builtin_amdgcn_mfma_f32_16x16x32_bf16(ah, Bhi[2][kf], a2, 0,0,0); \
            a2 = __builtin_amdgcn_mfma_f32_16x16x32_bf16(ah, Blo[2][kf], a2, 0,0,0); \
            a2 = __builtin_amdgcn_mfma_f32_16x16x32_bf16(al, Bhi[2][kf], a2, 0,0,0); \
            a3 = __builtin_amdgcn_mfma_f32_16x16x32_bf16(ah, Bhi[3][kf], a3, 0,0,0); \
            a3 = __builtin_amdgcn_mfma_f32_16x16x32_bf16(ah, Blo[3][kf], a3, 0,0,0); \
            a3 = __builtin_amdgcn_mfma_f32_16x16x32_bf16(al, Bhi[3][kf], a3, 0,0,0); \
        }                                                                     \
        _Pragma("unroll")                                                     \
        for (int r = 0; r < 4; ++r) {                                         \
            (RS)[r * 2048 + (0 * 8 + w) * 64 + l] = a0[r];                    \
            (RS)[r * 2048 + (1 * 8 + w) * 64 + l] = a1[r];                    \
            (RS)[r * 2048 + (2 * 8 + w) * 64 + l] = a2[r];                    \
            (RS)[r * 2048 + (3 * 8 + w) * 64 + l] = a3[r];                    \
        }                                                                     \
    } while (0)

#define ZERO_SCATTER(RS)                                                      \
    do {                                                                      \
        _Pragma("unroll")                                                     \
        for (int r = 0; r < 4; ++r)                                           \
            _Pragma("unroll")                                                 \
            for (int ct = 0; ct < 4; ++ct)                                    \
                (RS)[r * 2048 + (ct * 8 + w) * 64 + l] = 0.f;                 \
    } while (0)

#define GATE_BODY(ZSRC, TC, STORE_HT, PAR)                                    \
    do {                                                                      \
        float z[4];                                                           \
        _Pragma("unroll")                                                     \
        for (int ct = 0; ct < 4; ++ct) {                                      \
            float s = 0.f;                                                    \
            _Pragma("unroll")                                                 \
            for (int w2 = 0; w2 < 8; ++w2)                                    \
                s += (ZSRC)[w * 2048 + (ct * 8 + w2) * 64 + l];               \
            z[ct] = s + xzr[ct];                                              \
        }                                                                     \
        float i_ = fsig(z[0]);                                                \
        float f_ = fsig(z[1]);                                                \
        float g_ = ftanh(z[2]);                                               \
        float o_ = fsig(z[3]);                                                \
        float c_new = f_ * c1 + i_ * g_;                                      \
        float h_new = o_ * ftanh(c_new);                                      \
        bool  m  = (tokT[(TC) * 16 + bl] != 0);                               \
        float h2 = m ? h_new : h1;                                            \
        c1 = m ? c_new : c1;                                                  \
        h1 = h2;                                                              \
        if (STORE_HT) {                                                       \
            unsigned short hh = f2bf(h2);                                     \
            unsigned short hl = f2bf(h2 - bf2f(hh));                          \
            unsigned pack = ((unsigned)hh << 16) | hl;                        \
            __hip_atomic_store(&hT[(size_t)(PAR) * (H_ * 16) + u * 16 + bl],  \
                               pack, __ATOMIC_RELAXED, __HIP_MEMORY_SCOPE_AGENT); \
        }                                                                     \
        hseq[((size_t)bl * T_ + (TC)) * H_ + u] = h2;                         \
    } while (0)

__global__ __launch_bounds__(512, 1)
void lstm_pers_k(const float* __restrict__ xz,   // [B*T][4H]
                 const uint4* __restrict__ WhF,
                 float* __restrict__ hseq,       // [B*T][H]
                 unsigned* __restrict__ hT,      // [2][H][16] packed bf16 pair
                 const int* __restrict__ tokens,
                 unsigned* __restrict__ flags)   // [128]: A=0..63, B=64..127
{
    __shared__ float RsA[4 * 2048];               // 32 KB
    __shared__ float RsB[4 * 2048];               // 32 KB
    __shared__ int   tokT[T_ * 16];               // 16 KB, transposed [t][b]

    unsigned* flagsA = flags;
    unsigned* flagsB = flags + 64;

    const int tid = threadIdx.x;
    const int bx  = blockIdx.x;                   // 0..63
    const int w   = tid >> 6;
    const int l   = tid & 63;
    const int l15 = l & 15, lhi = l >> 4;
    const int u   = bx * 16 + l15;

    for (int i = tid; i < B_ * T_; i += 512)
        tokT[(i & 255) * 16 + (i >> 8)] = tokens[i];

    // one-time load of Wh fragments (shared by both chains), pinned
    short8 Bhi[4][4], Blo[4][4];
    {
        const uint4* p = WhF + (((size_t)bx * 8 + w) * 32) * 64;
        #pragma unroll
        for (int ct = 0; ct < 4; ++ct)
            #pragma unroll
            for (int kf = 0; kf < 4; ++kf) {
                uint4 hv = p[((ct * 4 + kf) * 2 + 0) * 64 + l];
                uint4 lv = p[((ct * 4 + kf) * 2 + 1) * 64 + l];
                Bhi[ct][kf] = *(short8*)&hv;
                Blo[ct][kf] = *(short8*)&lv;
            }
    }
    #pragma unroll
    for (int ct = 0; ct < 4; ++ct)
        #pragma unroll
        for (int kf = 0; kf < 4; ++kf) {
            asm volatile("" : "+v"(Bhi[ct][kf]));
            asm volatile("" : "+v"(Blo[ct][kf]));
        }
    __syncthreads();                              // tokT ready

    const bool gw  = (w < 4);
    const bool isA = (lhi < 2);                   // chain of this gate lane
    const int  bl  = lhi * 4 + w;                 // gate-lane batch 0..15
    float c1 = 0.f, h1 = 0.f;

    for (int t = 0; t < T_; ++t) {
        const int par = (t - 1) & 1;              // parity of h(t-1)

        // issue xz loads first (counted wait), then A h-loads
        float xzr[4];
        if (gw && (isA || t > 0)) {
            int tc = isA ? t : t - 1;
            size_t bt = (size_t)bl * T_ + tc;
            #pragma unroll
            for (int ct = 0; ct < 4; ++ct) {
                const float* ap = xz + bt * 4096 + (size_t)ct * H_ + u;
                asm volatile("global_load_dword %0, %1, off"
                             : "=&v"(xzr[ct]) : "v"(ap));
            }
        }
        unsigned hd[4][8];
        if (t > 0) {                              // Ph1: A h(t-1) loads
            const unsigned* hTp = hT + (size_t)par * (H_ * 16);
            #pragma unroll
            for (int kf = 0; kf < 4; ++kf) {
                const int k0 = w * 128 + kf * 32 + 8 * lhi;
                #pragma unroll
                for (int j = 0; j < 8; ++j) {
                    const unsigned* ap = hTp + (k0 + j) * 16 + l15;
                    asm volatile("global_load_dword %0, %1, off sc0 sc1"
                                 : "=&v"(hd[kf][j]) : "v"(ap));
                }
            }
        }

        // Ph2: B-gate(t-1) overlapping A h-load RTT
        if (t > 0 && gw) {
            asm volatile("s_waitcnt vmcnt(32)" ::: "memory");  // xz arrived
            __builtin_amdgcn_sched_barrier(0);
            if (!isA) GATE_BODY(RsB, t - 1, true, par);
        }
        // drain: A h-loads || B hT-stores (concurrent RTTs)
        asm volatile("s_waitcnt vmcnt(0)" ::: "memory");
        __builtin_amdgcn_sched_barrier(0);

        // Ph3: A MFMA(t)
        if (t > 0) MFMA_SCATTER(RsA); else ZERO_SCATTER(RsA);
        __syncthreads();

        // flagsB publish + poll (wave 0 only)
        if (t > 0 && w == 0) {
            if (l == 0)
                __hip_atomic_store(&flagsB[bx], (unsigned)t,
                                   __ATOMIC_RELAXED, __HIP_MEMORY_SCOPE_AGENT);
            while (true) {
                unsigned fv = __hip_atomic_load(&flagsB[l],
                    __ATOMIC_RELAXED, __HIP_MEMORY_SCOPE_AGENT);
                if (__all(fv >= (unsigned)t)) break;
                __builtin_amdgcn_s_sleep(1);
            }
        }
        __syncthreads();

        // Ph4b: B h(t-1) loads (same parity)
        if (t > 0) {
            const unsigned* hTp = hT + (size_t)par * (H_ * 16);
            #pragma unroll
            for (int kf = 0; kf < 4; ++kf) {
                const int k0 = w * 128 + kf * 32 + 8 * lhi;
                #pragma unroll
                for (int j = 0; j < 8; ++j) {
                    const unsigned* ap = hTp + (k0 + j) * 16 + l15;
                    asm volatile("global_load_dword %0, %1, off sc0 sc1"
                                 : "=&v"(hd[kf][j]) : "v"(ap));
                }
            }
        }
        // Ph5: A-gate(t) overlapping B h-load RTT
        if (gw && isA) GATE_BODY(RsA, t, (t + 1 < T_), t & 1);
        // drain: B h-loads || A hT-stores (concurrent RTTs)
        asm volatile("s_waitcnt vmcnt(0)" ::: "memory");
        __builtin_amdgcn_sched_barrier(0);

        // Ph6: B MFMA(t)
        if (t > 0) MFMA_SCATTER(RsB); else ZERO_SCATTER(RsB);
        __syncthreads();

        // flagsA publish + poll (wave 0 only)
        if (t + 1 < T_ && w == 0) {
            if (l == 0)
                __hip_atomic_store(&flagsA[bx], (unsigned)(t + 1),
                                   __ATOMIC_RELAXED, __HIP_MEMORY_SCOPE_AGENT);
            while (true) {
                unsigned fv = __hip_atomic_load(&flagsA[l],
                    __ATOMIC_RELAXED, __HIP_MEMORY_SCOPE_AGENT);
                if (__all(fv >= (unsigned)(t + 1))) break;
                __builtin_amdgcn_s_sleep(1);
            }
        }
        __syncthreads();
    }

    // epilogue: B-gate(T-1) from RsB (computed at t = T-1 Ph6)
    if (gw && !isA) {
        size_t bt = (size_t)bl * T_ + (T_ - 1);
        float xzr[4];
        #pragma unroll
        for (int ct = 0; ct < 4; ++ct)
            xzr[ct] = xz[bt * 4096 + (size_t)ct * H_ + u];
        GATE_BODY(RsB, T_ - 1, false, 0);
    }
}

// ---------------------------------------------------------------------------
extern "C" void kernel_launch(void* const* d_in, const int* in_sizes, int n_in,
                              void* d_out, int out_size, void* d_ws, size_t ws_size,
                              hipStream_t stream)
{
    const int*   tokens = (const int*)d_in[0];
    const float* emb    = (const float*)d_in[1];
    const float* Wx0    = (const float*)d_in[2];
    const float* Wh0    = (const float*)d_in[3];
    const float* b0     = (const float*)d_in[4];
    const float* Wx1    = (const float*)d_in[5];
    const float* Wh1    = (const float*)d_in[6];
    const float* b1     = (const float*)d_in[7];
    const float* Wout   = (const float*)d_in[8];
    const float* bout   = (const float*)d_in[9];
    float* out = (float*)d_out;

    // d_ws: bf16 planes (~82.3 MB) + hT double buffer (128 KB) + flags
    unsigned short* wsu = (unsigned short*)d_ws;
    const size_t BPL = (size_t)16000 * 1024;          // B-plane slot (shorts)
    const size_t AP  = (size_t)4096 * 1024;           // A-plane slot (shorts)
    unsigned short* Bh  = wsu;
    unsigned short* Bl  = wsu + BPL;
    unsigned short* Ahp = wsu + 2 * BPL;
    unsigned short* Alp = Ahp + AP;
    unsigned* hT    = (unsigned*)(wsu + 2 * BPL + 2 * AP);   // 2*16384 u32
    unsigned* flags = hT + 2 * (size_t)H_ * 16;              // 128 words

    // d_out head used as fp32 scratch; all dead before final GEMM writes logits.
    float* f   = (float*)d_out;
    float* xz  = f;                                   // 16.78M floats
    float* WhF = xz + (size_t)4096 * 4096;            // 4.19M (frag image)
    float* h0  = WhF + (size_t)1024 * 4096;           // 4.19M
    float* h1  = h0 + (size_t)4096 * 1024;            // 4.19M

    dim3 blk(256);

    // ---- layer 0 input projection ----
    gather_cvt_k<<<2048, blk, 0, stream>>>(tokens, emb, Ahp, Alp);
    twz_k<<<dim3(128, 16), blk, 0, stream>>>(Wx0, Bh, Bl, 512, 4096, 0);
    mgemm_k<0><<<dim3(32, 32), blk, 0, stream>>>(Ahp, Alp, Bh, Bl, b0, xz,
                                                 nullptr, 512, 4096, 0);
    // ---- layer 0 recurrence (persistent, two-chain pipeline) ----
    wprep_k<<<2048, blk, 0, stream>>>(Wh0, (uint4*)WhF, flags);
    {
        void* args[] = {(void*)&xz, (void*)&WhF, (void*)&h0, (void*)&hT,
                        (void*)&tokens, (void*)&flags};
        hipLaunchCooperativeKernel((void*)lstm_pers_k, dim3(64), dim3(512),
                                   args, 0, stream);
    }
    // ---- layer 1 input projection ----
    cvt_k<<<4096, blk, 0, stream>>>(h0, Ahp, Alp);
    twz_k<<<dim3(128, 32), blk, 0, stream>>>(Wx1, Bh, Bl, 1024, 4096, 0);
    mgemm_k<0><<<dim3(32, 32), blk, 0, stream>>>(Ahp, Alp, Bh, Bl, b1, xz,
                                                 nullptr, 1024, 4096, 0);
    // ---- layer 1 recurrence (persistent, two-chain pipeline) ----
    wprep_k<<<2048, blk, 0, stream>>>(Wh1, (uint4*)WhF, flags);
    {
        void* args[] = {(void*)&xz, (void*)&WhF, (void*)&h1, (void*)&hT,
                        (void*)&tokens, (void*)&flags};
        hipLaunchCooperativeKernel((void*)lstm_pers_k, dim3(64), dim3(512),
                                   args, 0, stream);
    }
    // ---- vocab projection in two N-halves (bounds ws usage) ----
    cvt_k<<<4096, blk, 0, stream>>>(h1, Ahp, Alp);
    twz_k<<<dim3(500, 32), blk, 0, stream>>>(Wout, Bh, Bl, 1024, 32000, 0);
    mgemm_k<1><<<dim3(125, 32), blk, 0, stream>>>(Ahp, Alp, Bh, Bl, bout, out,
                                                  tokens, 1024, 32000, 0);
    twz_k<<<dim3(500, 32), blk, 0, stream>>>(Wout, Bh, Bl, 1024, 32000, 16000);
    mgemm_k<1><<<dim3(125, 32), blk, 0, stream>>>(Ahp, Alp, Bh, Bl, bout, out,
                                                  tokens, 1024, 32000, 16000);
}

// Round 14
// 3878.094 us; speedup vs baseline: 1.5900x; 1.5900x over previous
//
#include <hip/hip_runtime.h>

#define B_ 16
#define T_ 256
#define E_ 512
#define H_ 1024
#define V_ 32000

typedef float f32x4 __attribute__((ext_vector_type(4)));
typedef short short8 __attribute__((ext_vector_type(8)));

typedef __attribute__((address_space(1))) const void gas_t;
typedef __attribute__((address_space(3))) void las_t;

__device__ __forceinline__ unsigned short f2bf(float x) {
    unsigned int u = __float_as_uint(x);
    u += 0x7FFF + ((u >> 16) & 1);            // RTNE
    return (unsigned short)(u >> 16);
}
__device__ __forceinline__ float bf2f(unsigned short b) {
    return __uint_as_float(((unsigned int)b) << 16);
}
// fast gates: v_exp + fast-div; saturation-safe, ~2e-7 error
__device__ __forceinline__ float fsig(float x) {
    return __fdividef(1.f, 1.f + __expf(-x));
}
__device__ __forceinline__ float ftanh(float x) {
    float xc = fminf(fmaxf(x, -15.f), 15.f);
    float e  = __expf(-2.f * xc);
    return __fdividef(1.f - e, 1.f + e);
}

// ---------------------------------------------------------------------------
// Embedding gather fused with bf16 hi/lo split: emb[tokens] -> Ah/Al [4096,512]
// ---------------------------------------------------------------------------
__global__ __launch_bounds__(256)
void gather_cvt_k(const int* __restrict__ tokens, const float* __restrict__ emb,
                  unsigned short* __restrict__ Ah, unsigned short* __restrict__ Al)
{
    int i  = blockIdx.x * 256 + threadIdx.x;   // float4 id; 4096*128 total
    int bt = i >> 7;
    int e4 = i & 127;
    float4 v = ((const float4*)(emb + (size_t)tokens[bt] * E_))[e4];
    ushort4 h, l;
    h.x = f2bf(v.x); l.x = f2bf(v.x - bf2f(h.x));
    h.y = f2bf(v.y); l.y = f2bf(v.y - bf2f(h.y));
    h.z = f2bf(v.z); l.z = f2bf(v.z - bf2f(h.z));
    h.w = f2bf(v.w); l.w = f2bf(v.w - bf2f(h.w));
    ((ushort4*)Ah)[i] = h;
    ((ushort4*)Al)[i] = l;
}

// ---------------------------------------------------------------------------
// fp32 -> bf16 hi/lo split (A activations, row-major, no transpose)
// ---------------------------------------------------------------------------
__global__ __launch_bounds__(256)
void cvt_k(const float* __restrict__ A, unsigned short* __restrict__ Ah,
           unsigned short* __restrict__ Al)
{
    int i = blockIdx.x * 256 + threadIdx.x;    // float4 id
    float4 v = ((const float4*)A)[i];
    ushort4 h, l;
    h.x = f2bf(v.x); l.x = f2bf(v.x - bf2f(h.x));
    h.y = f2bf(v.y); l.y = f2bf(v.y - bf2f(h.y));
    h.z = f2bf(v.z); l.z = f2bf(v.z - bf2f(h.z));
    h.w = f2bf(v.w); l.w = f2bf(v.w - bf2f(h.w));
    ((ushort4*)Ah)[i] = h;
    ((ushort4*)Al)[i] = l;
}

// ---------------------------------------------------------------------------
// Weight transpose + split: W fp32 [K][Nfull], col slice [n0, n0+NS) ->
// Bh/Bl bf16 [NS][K]. 32x32 LDS tiles, +1 pad, coalesced both sides.
// ---------------------------------------------------------------------------
__global__ __launch_bounds__(256)
void twz_k(const float* __restrict__ W, unsigned short* __restrict__ Bh,
           unsigned short* __restrict__ Bl, int Kd, int Nfull, int n0)
{
    __shared__ float tile[32][33];
    int t  = threadIdx.x;
    int tx = t & 31, ty = t >> 5;              // ty 0..7
    int nb = blockIdx.x * 32, kb = blockIdx.y * 32;
    #pragma unroll
    for (int i = 0; i < 4; ++i)
        tile[ty + i * 8][tx] = W[(size_t)(kb + ty + i * 8) * Nfull + n0 + nb + tx];
    __syncthreads();
    #pragma unroll
    for (int i = 0; i < 4; ++i) {
        float v = tile[tx][ty + i * 8];
        unsigned short h = f2bf(v), l = f2bf(v - bf2f(h));
        size_t o = (size_t)(nb + ty + i * 8) * Kd + kb + tx;
        Bh[o] = h; Bl[o] = l;
    }
}

// ---------------------------------------------------------------------------
// Split-bf16 3-pass MFMA GEMM (round-5-verified core) + bijective XCD swizzle.
// ---------------------------------------------------------------------------
template<int DO_MASK>
__global__ __launch_bounds__(256)
void mgemm_k(const unsigned short* __restrict__ Ah, const unsigned short* __restrict__ Al,
             const unsigned short* __restrict__ Bh, const unsigned short* __restrict__ Bl,
             const float* __restrict__ bias, float* __restrict__ C,
             const int* __restrict__ tokens, int K, int ldc, int n0)
{
    __shared__ unsigned short LDSS[4][128 * 64];   // 64 KB: Ah,Al,Bh,Bl planes

    const int tid  = threadIdx.x;
    // bijective XCD swizzle: lin = 8q+r -> r*(nwg/8)+q
    const int nwg = gridDim.x * gridDim.y;
    int lin = blockIdx.y * gridDim.x + blockIdx.x;
    lin = (lin & 7) * (nwg >> 3) + (lin >> 3);
    const int bm   = (lin / gridDim.x) * 128;
    const int bn   = (lin % gridDim.x) * 128;
    const int w    = tid >> 6, lane = tid & 63;
    const int wm   = (w >> 1) * 64, wn = (w & 1) * 64;
    const int l15  = lane & 15, lhi = lane >> 4;

    const unsigned short* gp = (w == 0) ? Ah : (w == 1) ? Al : (w == 2) ? Bh : Bl;
    const int rb = (w < 2) ? bm : bn;
    const int srow = lane >> 3;
    const int scol = (lane & 7) ^ srow;
    unsigned short* lbase = &LDSS[w][0];

    f32x4 acc[4][4];
    #pragma unroll
    for (int mi = 0; mi < 4; ++mi)
        #pragma unroll
        for (int ni = 0; ni < 4; ++ni) {
            f32x4 z = {0.f, 0.f, 0.f, 0.f};
            acc[mi][ni] = z;
        }

    for (int kt = 0; kt < K; kt += 64) {
        #pragma unroll
        for (int c = 0; c < 16; ++c) {
            const unsigned short* src =
                gp + (size_t)(rb + c * 8 + srow) * K + kt + scol * 8;
            __builtin_amdgcn_global_load_lds((gas_t*)src,
                                             (las_t*)(lbase + c * 512), 16, 0, 0);
        }
        __syncthreads();
        #pragma unroll
        for (int ks = 0; ks < 2; ++ks) {
            short8 ah[4], al[4], bh[4], bl[4];
            const int s = ks * 4 + lhi;
            #pragma unroll
            for (int mi = 0; mi < 4; ++mi) {
                int m = wm + mi * 16 + l15;
                int off = m * 64 + ((s ^ (m & 7)) * 8);
                ah[mi] = *(const short8*)(&LDSS[0][off]);
                al[mi] = *(const short8*)(&LDSS[1][off]);
            }
            #pragma unroll
            for (int ni = 0; ni < 4; ++ni) {
                int n = wn + ni * 16 + l15;
                int off = n * 64 + ((s ^ (n & 7)) * 8);
                bh[ni] = *(const short8*)(&LDSS[2][off]);
                bl[ni] = *(const short8*)(&LDSS[3][off]);
            }
            #pragma unroll
            for (int mi = 0; mi < 4; ++mi)
                #pragma unroll
                for (int ni = 0; ni < 4; ++ni) {
                    acc[mi][ni] = __builtin_amdgcn_mfma_f32_16x16x32_bf16(
                        ah[mi], bh[ni], acc[mi][ni], 0, 0, 0);
                    acc[mi][ni] = __builtin_amdgcn_mfma_f32_16x16x32_bf16(
                        ah[mi], bl[ni], acc[mi][ni], 0, 0, 0);
                    acc[mi][ni] = __builtin_amdgcn_mfma_f32_16x16x32_bf16(
                        al[mi], bh[ni], acc[mi][ni], 0, 0, 0);
                }
        }
        __syncthreads();
    }

    #pragma unroll
    for (int mi = 0; mi < 4; ++mi) {
        #pragma unroll
        for (int r = 0; r < 4; ++r) {
            int row = bm + wm + mi * 16 + lhi * 4 + r;
            bool msk = true;
            if (DO_MASK) msk = (tokens[row] != 0);
            #pragma unroll
            for (int ni = 0; ni < 4; ++ni) {
                int col = bn + wn + ni * 16 + l15;
                float v = acc[mi][ni][r] + bias[n0 + col];
                if (DO_MASK && !msk) v = ((n0 + col) == 0) ? 1.f : 0.f;
                C[(size_t)row * ldc + n0 + col] = v;
            }
        }
    }
}

// ---------------------------------------------------------------------------
// Wh [1024][4096] fp32 -> register-fragment image WhF (bf16 hi/lo B-frags).
// Also resets the 64 packed per-block barrier flags.
// ---------------------------------------------------------------------------
__global__ __launch_bounds__(256)
void wprep_k(const float* __restrict__ Wh, uint4* __restrict__ WhF,
             unsigned* __restrict__ flags)
{
    int flat = blockIdx.x * 256 + threadIdx.x;      // 0 .. 524287
    if (flat < 64) flags[flat] = 0;
    int l  = flat & 63;
    int kf = (flat >> 6) & 3;
    int ct = (flat >> 8) & 3;
    int w  = (flat >> 10) & 7;
    int bx = flat >> 13;                            // 0..63
    int k0  = w * 128 + kf * 32 + 8 * (l >> 4);
    int col = ct * H_ + bx * 16 + (l & 15);
    unsigned short hi[8], lo[8];
    #pragma unroll
    for (int j = 0; j < 8; ++j) {
        float v = Wh[(size_t)(k0 + j) * (4 * H_) + col];
        hi[j] = f2bf(v); lo[j] = f2bf(v - bf2f(hi[j]));
    }
    size_t base = ((((size_t)bx * 8 + w) * 4 + ct) * 4 + kf) * 2;
    WhF[(base + 0) * 64 + l] = *(uint4*)hi;
    WhF[(base + 1) * 64 + l] = *(uint4*)lo;
}

// ---------------------------------------------------------------------------
// Persistent MFMA LSTM layer — round-9/11/12 structure (proven optimum:
// 1437 us/layer). Pipelined raw sc0/sc1 h-loads (packed bf16 pairs), 4-wave
// gate split with scalar r-plane LDS reduce, fast gates, single-wave-0
// word-flag barrier, weights pinned in registers, launch_bounds(512,1).
// ---------------------------------------------------------------------------
__global__ __launch_bounds__(512, 1)
void lstm_pers_k(const float* __restrict__ xz,   // [B*T][4H]
                 const uint4* __restrict__ WhF,
                 float* __restrict__ hseq,       // [B*T][H]
                 unsigned* __restrict__ hT,      // [2][H][16] packed bf16 pair
                 const int* __restrict__ tokens,
                 unsigned* __restrict__ flags)
{
    __shared__ float Rs2[4 * 2048];               // 32 KB: r-plane scalar layout

    const int tid = threadIdx.x;
    const int bx  = blockIdx.x;                   // 0..63
    const int w   = tid >> 6;
    const int l   = tid & 63;
    const int l15 = l & 15, lhi = l >> 4;
    const int u   = bx * 16 + l15;

    // one-time load of Wh fragments, then PIN in registers (opaque asm)
    short8 Bhi[4][4], Blo[4][4];
    {
        const uint4* p = WhF + (((size_t)bx * 8 + w) * 32) * 64;
        #pragma unroll
        for (int ct = 0; ct < 4; ++ct)
            #pragma unroll
            for (int kf = 0; kf < 4; ++kf) {
                uint4 hv = p[((ct * 4 + kf) * 2 + 0) * 64 + l];
                uint4 lv = p[((ct * 4 + kf) * 2 + 1) * 64 + l];
                Bhi[ct][kf] = *(short8*)&hv;
                Blo[ct][kf] = *(short8*)&lv;
            }
    }
    #pragma unroll
    for (int ct = 0; ct < 4; ++ct)
        #pragma unroll
        for (int kf = 0; kf < 4; ++kf) {
            asm volatile("" : "+v"(Bhi[ct][kf]));
            asm volatile("" : "+v"(Blo[ct][kf]));
        }

    float c1 = 0.f, h1 = 0.f;                     // gate-wave cell state
    const size_t bt_base = (size_t)(lhi * 4 + w) * T_;  // gate-wave batch row

    for (int t = 0; t < T_; ++t) {
        // prefetch xz + token for this step (gate waves only; compiler sinks
        // the waitcnt to the gate phase -> overlaps h-load + MFMA)
        float xzr[4];
        int tok = 0;
        if (w < 4) {
            size_t bt = bt_base + t;
            #pragma unroll
            for (int ct = 0; ct < 4; ++ct)
                xzr[ct] = xz[bt * 4096 + (size_t)ct * H_ + u];
            tok = tokens[bt];
        }

        if (t > 0) {
            // pipelined MALL-coherent h loads (packed bf16 pairs)
            const unsigned* hTp = hT + (size_t)((t - 1) & 1) * (H_ * 16);
            unsigned hd[4][8];
            #pragma unroll
            for (int kf = 0; kf < 4; ++kf) {
                const int k0 = w * 128 + kf * 32 + 8 * lhi;
                #pragma unroll
                for (int j = 0; j < 8; ++j) {
                    const unsigned* ap = hTp + (k0 + j) * 16 + l15;
                    asm volatile("global_load_dword %0, %1, off sc0 sc1"
                                 : "=&v"(hd[kf][j]) : "v"(ap));
                }
            }
            asm volatile("s_waitcnt vmcnt(0)" ::: "memory");
            __builtin_amdgcn_sched_barrier(0);

            f32x4 acc0 = {0.f,0.f,0.f,0.f}, acc1 = acc0, acc2 = acc0, acc3 = acc0;
            #pragma unroll
            for (int kf = 0; kf < 4; ++kf) {
                unsigned short hh[8], hl[8];
                #pragma unroll
                for (int j = 0; j < 8; ++j) {
                    unsigned d = hd[kf][j];
                    hh[j] = (unsigned short)(d >> 16);
                    hl[j] = (unsigned short)(d & 0xFFFFu);
                }
                short8 ah = *(short8*)hh, al = *(short8*)hl;
                acc0 = __builtin_amdgcn_mfma_f32_16x16x32_bf16(ah, Bhi[0][kf], acc0, 0,0,0);
                acc0 = __builtin_amdgcn_mfma_f32_16x16x32_bf16(ah, Blo[0][kf], acc0, 0,0,0);
                acc0 = __builtin_amdgcn_mfma_f32_16x16x32_bf16(al, Bhi[0][kf], acc0, 0,0,0);
                acc1 = __builtin_amdgcn_mfma_f32_16x16x32_bf16(ah, Bhi[1][kf], acc1, 0,0,0);
                acc1 = __builtin_amdgcn_mfma_f32_16x16x32_bf16(ah, Blo[1][kf], acc1, 0,0,0);
                acc1 = __builtin_amdgcn_mfma_f32_16x16x32_bf16(al, Bhi[1][kf], acc1, 0,0,0);
                acc2 = __builtin_amdgcn_mfma_f32_16x16x32_bf16(ah, Bhi[2][kf], acc2, 0,0,0);
                acc2 = __builtin_amdgcn_mfma_f32_16x16x32_bf16(ah, Blo[2][kf], acc2, 0,0,0);
                acc2 = __builtin_amdgcn_mfma_f32_16x16x32_bf16(al, Bhi[2][kf], acc2, 0,0,0);
                acc3 = __builtin_amdgcn_mfma_f32_16x16x32_bf16(ah, Bhi[3][kf], acc3, 0,0,0);
                acc3 = __builtin_amdgcn_mfma_f32_16x16x32_bf16(ah, Blo[3][kf], acc3, 0,0,0);
                acc3 = __builtin_amdgcn_mfma_f32_16x16x32_bf16(al, Bhi[3][kf], acc3, 0,0,0);
            }
            // scatter to scalar r-planes (conflict-free b32 stores)
            #pragma unroll
            for (int r = 0; r < 4; ++r) {
                Rs2[r * 2048 + (0 * 8 + w) * 64 + l] = acc0[r];
                Rs2[r * 2048 + (1 * 8 + w) * 64 + l] = acc1[r];
                Rs2[r * 2048 + (2 * 8 + w) * 64 + l] = acc2[r];
                Rs2[r * 2048 + (3 * 8 + w) * 64 + l] = acc3[r];
            }
        }
        __syncthreads();

        // gate phase: waves 0-3 in parallel, wave w = batch-group r=w
        if (w < 4) {
            float z[4];
            #pragma unroll
            for (int ct = 0; ct < 4; ++ct) {
                float s = 0.f;
                if (t > 0) {
                    #pragma unroll
                    for (int w2 = 0; w2 < 8; ++w2)
                        s += Rs2[w * 2048 + (ct * 8 + w2) * 64 + l];
                }
                z[ct] = s + xzr[ct];
            }
            float i_ = fsig(z[0]);
            float f_ = fsig(z[1]);
            float g_ = ftanh(z[2]);
            float o_ = fsig(z[3]);
            float c_new = f_ * c1 + i_ * g_;
            float h_new = o_ * ftanh(c_new);
            bool  m  = (tok != 0);
            float h2 = m ? h_new : h1;
            c1 = m ? c_new : c1;
            h1 = h2;
            size_t bt = bt_base + t;
            if (t + 1 < T_) {
                unsigned short hh = f2bf(h2);
                unsigned short hl = f2bf(h2 - bf2f(hh));
                unsigned pack = ((unsigned)hh << 16) | hl;
                __hip_atomic_store(&hT[(size_t)(t & 1) * (H_ * 16) + u * 16 +
                                       (lhi * 4 + w)], pack,
                                   __ATOMIC_RELAXED, __HIP_MEMORY_SCOPE_AGENT);
                asm volatile("s_waitcnt vmcnt(0)" ::: "memory");  // hT drained
            }
            hseq[bt * H_ + u] = h2;               // off critical path
        }
        __syncthreads();                          // all gate hT stores drained

        if (w == 0 && t + 1 < T_) {
            if (l == 0)
                __hip_atomic_store(&flags[bx], (unsigned)(t + 1),
                                   __ATOMIC_RELAXED, __HIP_MEMORY_SCOPE_AGENT);
            const unsigned tgt = (unsigned)(t + 1);
            while (true) {
                unsigned fv = __hip_atomic_load(&flags[l],
                    __ATOMIC_RELAXED, __HIP_MEMORY_SCOPE_AGENT);
                if (__all(fv >= tgt)) break;
                __builtin_amdgcn_s_sleep(1);
            }
        }
        __syncthreads();                          // release for next step
    }
}

// ---------------------------------------------------------------------------
extern "C" void kernel_launch(void* const* d_in, const int* in_sizes, int n_in,
                              void* d_out, int out_size, void* d_ws, size_t ws_size,
                              hipStream_t stream)
{
    const int*   tokens = (const int*)d_in[0];
    const float* emb    = (const float*)d_in[1];
    const float* Wx0    = (const float*)d_in[2];
    const float* Wh0    = (const float*)d_in[3];
    const float* b0     = (const float*)d_in[4];
    const float* Wx1    = (const float*)d_in[5];
    const float* Wh1    = (const float*)d_in[6];
    const float* b1     = (const float*)d_in[7];
    const float* Wout   = (const float*)d_in[8];
    const float* bout   = (const float*)d_in[9];
    float* out = (float*)d_out;

    // d_ws: bf16 planes (~82.3 MB) + hT double buffer (128 KB) + flags
    unsigned short* wsu = (unsigned short*)d_ws;
    const size_t BPL = (size_t)16000 * 1024;          // B-plane slot (shorts)
    const size_t AP  = (size_t)4096 * 1024;           // A-plane slot (shorts)
    unsigned short* Bh  = wsu;
    unsigned short* Bl  = wsu + BPL;
    unsigned short* Ahp = wsu + 2 * BPL;
    unsigned short* Alp = Ahp + AP;
    unsigned* hT    = (unsigned*)(wsu + 2 * BPL + 2 * AP);   // 2*16384 u32
    unsigned* flags = hT + 2 * (size_t)H_ * 16;              // 64 words

    // d_out head used as fp32 scratch; all dead before final GEMM writes logits.
    float* f   = (float*)d_out;
    float* xz  = f;                                   // 16.78M floats
    float* WhF = xz + (size_t)4096 * 4096;            // 4.19M (frag image)
    float* h0  = WhF + (size_t)1024 * 4096;           // 4.19M
    float* h1  = h0 + (size_t)4096 * 1024;            // 4.19M

    dim3 blk(256);

    // ---- layer 0 input projection ----
    gather_cvt_k<<<2048, blk, 0, stream>>>(tokens, emb, Ahp, Alp);
    twz_k<<<dim3(128, 16), blk, 0, stream>>>(Wx0, Bh, Bl, 512, 4096, 0);
    mgemm_k<0><<<dim3(32, 32), blk, 0, stream>>>(Ahp, Alp, Bh, Bl, b0, xz,
                                                 nullptr, 512, 4096, 0);
    // ---- layer 0 recurrence (persistent) ----
    wprep_k<<<2048, blk, 0, stream>>>(Wh0, (uint4*)WhF, flags);
    {
        void* args[] = {(void*)&xz, (void*)&WhF, (void*)&h0, (void*)&hT,
                        (void*)&tokens, (void*)&flags};
        hipLaunchCooperativeKernel((void*)lstm_pers_k, dim3(64), dim3(512),
                                   args, 0, stream);
    }
    // ---- layer 1 input projection ----
    cvt_k<<<4096, blk, 0, stream>>>(h0, Ahp, Alp);
    twz_k<<<dim3(128, 32), blk, 0, stream>>>(Wx1, Bh, Bl, 1024, 4096, 0);
    mgemm_k<0><<<dim3(32, 32), blk, 0, stream>>>(Ahp, Alp, Bh, Bl, b1, xz,
                                                 nullptr, 1024, 4096, 0);
    // ---- layer 1 recurrence (persistent) ----
    wprep_k<<<2048, blk, 0, stream>>>(Wh1, (uint4*)WhF, flags);
    {
        void* args[] = {(void*)&xz, (void*)&WhF, (void*)&h1, (void*)&hT,
                        (void*)&tokens, (void*)&flags};
        hipLaunchCooperativeKernel((void*)lstm_pers_k, dim3(64), dim3(512),
                                   args, 0, stream);
    }
    // ---- vocab projection in two N-halves (bounds ws usage) ----
    cvt_k<<<4096, blk, 0, stream>>>(h1, Ahp, Alp);
    twz_k<<<dim3(500, 32), blk, 0, stream>>>(Wout, Bh, Bl, 1024, 32000, 0);
    mgemm_k<1><<<dim3(125, 32), blk, 0, stream>>>(Ahp, Alp, Bh, Bl, bout, out,
                                                  tokens, 1024, 32000, 0);
    twz_k<<<dim3(500, 32), blk, 0, stream>>>(Wout, Bh, Bl, 1024, 32000, 16000);
    mgemm_k<1><<<dim3(125, 32), blk, 0, stream>>>(Ahp, Alp, Bh, Bl, bout, out,
                                                  tokens, 1024, 32000, 16000);
}

// Round 15
// 2471.748 us; speedup vs baseline: 2.4946x; 1.5690x over previous
//
#include <hip/hip_runtime.h>

#define B_ 16
#define T_ 256
#define E_ 512
#define H_ 1024
#define V_ 32000
#define HX16 (H_ * 16)

typedef float f32x4 __attribute__((ext_vector_type(4)));
typedef short short8 __attribute__((ext_vector_type(8)));

typedef __attribute__((address_space(1))) const void gas_t;
typedef __attribute__((address_space(3))) void las_t;

__device__ __forceinline__ unsigned short f2bf(float x) {
    unsigned int u = __float_as_uint(x);
    u += 0x7FFF + ((u >> 16) & 1);            // RTNE
    return (unsigned short)(u >> 16);
}
__device__ __forceinline__ float bf2f(unsigned short b) {
    return __uint_as_float(((unsigned int)b) << 16);
}
__device__ __forceinline__ float fsig(float x) {
    return __fdividef(1.f, 1.f + __expf(-x));
}
__device__ __forceinline__ float ftanh(float x) {
    float xc = fminf(fmaxf(x, -15.f), 15.f);
    float e  = __expf(-2.f * xc);
    return __fdividef(1.f - e, 1.f + e);
}

// ---------------------------------------------------------------------------
__global__ __launch_bounds__(256)
void gather_cvt_k(const int* __restrict__ tokens, const float* __restrict__ emb,
                  unsigned short* __restrict__ Ah, unsigned short* __restrict__ Al)
{
    int i  = blockIdx.x * 256 + threadIdx.x;
    int bt = i >> 7;
    int e4 = i & 127;
    float4 v = ((const float4*)(emb + (size_t)tokens[bt] * E_))[e4];
    ushort4 h, l;
    h.x = f2bf(v.x); l.x = f2bf(v.x - bf2f(h.x));
    h.y = f2bf(v.y); l.y = f2bf(v.y - bf2f(h.y));
    h.z = f2bf(v.z); l.z = f2bf(v.z - bf2f(h.z));
    h.w = f2bf(v.w); l.w = f2bf(v.w - bf2f(h.w));
    ((ushort4*)Ah)[i] = h;
    ((ushort4*)Al)[i] = l;
}

// ---------------------------------------------------------------------------
__global__ __launch_bounds__(256)
void cvt_k(const float* __restrict__ A, unsigned short* __restrict__ Ah,
           unsigned short* __restrict__ Al)
{
    int i = blockIdx.x * 256 + threadIdx.x;
    float4 v = ((const float4*)A)[i];
    ushort4 h, l;
    h.x = f2bf(v.x); l.x = f2bf(v.x - bf2f(h.x));
    h.y = f2bf(v.y); l.y = f2bf(v.y - bf2f(h.y));
    h.z = f2bf(v.z); l.z = f2bf(v.z - bf2f(h.z));
    h.w = f2bf(v.w); l.w = f2bf(v.w - bf2f(h.w));
    ((ushort4*)Ah)[i] = h;
    ((ushort4*)Al)[i] = l;
}

// ---------------------------------------------------------------------------
__global__ __launch_bounds__(256)
void twz_k(const float* __restrict__ W, unsigned short* __restrict__ Bh,
           unsigned short* __restrict__ Bl, int Kd, int Nfull, int n0)
{
    __shared__ float tile[32][33];
    int t  = threadIdx.x;
    int tx = t & 31, ty = t >> 5;
    int nb = blockIdx.x * 32, kb = blockIdx.y * 32;
    #pragma unroll
    for (int i = 0; i < 4; ++i)
        tile[ty + i * 8][tx] = W[(size_t)(kb + ty + i * 8) * Nfull + n0 + nb + tx];
    __syncthreads();
    #pragma unroll
    for (int i = 0; i < 4; ++i) {
        float v = tile[tx][ty + i * 8];
        unsigned short h = f2bf(v), l = f2bf(v - bf2f(h));
        size_t o = (size_t)(nb + ty + i * 8) * Kd + kb + tx;
        Bh[o] = h; Bl[o] = l;
    }
}

// ---------------------------------------------------------------------------
// Split-bf16 3-pass MFMA GEMM (round-5-verified core) + bijective XCD swizzle.
// ---------------------------------------------------------------------------
template<int DO_MASK>
__global__ __launch_bounds__(256)
void mgemm_k(const unsigned short* __restrict__ Ah, const unsigned short* __restrict__ Al,
             const unsigned short* __restrict__ Bh, const unsigned short* __restrict__ Bl,
             const float* __restrict__ bias, float* __restrict__ C,
             const int* __restrict__ tokens, int K, int ldc, int n0)
{
    __shared__ unsigned short LDSS[4][128 * 64];

    const int tid  = threadIdx.x;
    const int nwg = gridDim.x * gridDim.y;
    int lin = blockIdx.y * gridDim.x + blockIdx.x;
    lin = (lin & 7) * (nwg >> 3) + (lin >> 3);
    const int bm   = (lin / gridDim.x) * 128;
    const int bn   = (lin % gridDim.x) * 128;
    const int w    = tid >> 6, lane = tid & 63;
    const int wm   = (w >> 1) * 64, wn = (w & 1) * 64;
    const int l15  = lane & 15, lhi = lane >> 4;

    const unsigned short* gp = (w == 0) ? Ah : (w == 1) ? Al : (w == 2) ? Bh : Bl;
    const int rb = (w < 2) ? bm : bn;
    const int srow = lane >> 3;
    const int scol = (lane & 7) ^ srow;
    unsigned short* lbase = &LDSS[w][0];

    f32x4 acc[4][4];
    #pragma unroll
    for (int mi = 0; mi < 4; ++mi)
        #pragma unroll
        for (int ni = 0; ni < 4; ++ni) {
            f32x4 z = {0.f, 0.f, 0.f, 0.f};
            acc[mi][ni] = z;
        }

    for (int kt = 0; kt < K; kt += 64) {
        #pragma unroll
        for (int c = 0; c < 16; ++c) {
            const unsigned short* src =
                gp + (size_t)(rb + c * 8 + srow) * K + kt + scol * 8;
            __builtin_amdgcn_global_load_lds((gas_t*)src,
                                             (las_t*)(lbase + c * 512), 16, 0, 0);
        }
        __syncthreads();
        #pragma unroll
        for (int ks = 0; ks < 2; ++ks) {
            short8 ah[4], al[4], bh[4], bl[4];
            const int s = ks * 4 + lhi;
            #pragma unroll
            for (int mi = 0; mi < 4; ++mi) {
                int m = wm + mi * 16 + l15;
                int off = m * 64 + ((s ^ (m & 7)) * 8);
                ah[mi] = *(const short8*)(&LDSS[0][off]);
                al[mi] = *(const short8*)(&LDSS[1][off]);
            }
            #pragma unroll
            for (int ni = 0; ni < 4; ++ni) {
                int n = wn + ni * 16 + l15;
                int off = n * 64 + ((s ^ (n & 7)) * 8);
                bh[ni] = *(const short8*)(&LDSS[2][off]);
                bl[ni] = *(const short8*)(&LDSS[3][off]);
            }
            #pragma unroll
            for (int mi = 0; mi < 4; ++mi)
                #pragma unroll
                for (int ni = 0; ni < 4; ++ni) {
                    acc[mi][ni] = __builtin_amdgcn_mfma_f32_16x16x32_bf16(
                        ah[mi], bh[ni], acc[mi][ni], 0, 0, 0);
                    acc[mi][ni] = __builtin_amdgcn_mfma_f32_16x16x32_bf16(
                        ah[mi], bl[ni], acc[mi][ni], 0, 0, 0);
                    acc[mi][ni] = __builtin_amdgcn_mfma_f32_16x16x32_bf16(
                        al[mi], bh[ni], acc[mi][ni], 0, 0, 0);
                }
        }
        __syncthreads();
    }

    #pragma unroll
    for (int mi = 0; mi < 4; ++mi) {
        #pragma unroll
        for (int r = 0; r < 4; ++r) {
            int row = bm + wm + mi * 16 + lhi * 4 + r;
            bool msk = true;
            if (DO_MASK) msk = (tokens[row] != 0);
            #pragma unroll
            for (int ni = 0; ni < 4; ++ni) {
                int col = bn + wn + ni * 16 + l15;
                float v = acc[mi][ni][r] + bias[n0 + col];
                if (DO_MASK && !msk) v = ((n0 + col) == 0) ? 1.f : 0.f;
                C[(size_t)row * ldc + n0 + col] = v;
            }
        }
    }
}

// ---------------------------------------------------------------------------
// W [1024][4096] fp32 -> register-fragment image (bf16 hi/lo B-frags).
// Also resets `nrst` flag words at `flags`.
// ---------------------------------------------------------------------------
__global__ __launch_bounds__(256)
void wprep_k(const float* __restrict__ Wh, uint4* __restrict__ WhF,
             unsigned* __restrict__ flags, int nrst)
{
    int flat = blockIdx.x * 256 + threadIdx.x;
    if (flat < nrst) flags[flat] = 0;
    int l  = flat & 63;
    int kf = (flat >> 6) & 3;
    int ct = (flat >> 8) & 3;
    int w  = (flat >> 10) & 7;
    int bx = flat >> 13;
    int k0  = w * 128 + kf * 32 + 8 * (l >> 4);
    int col = ct * H_ + bx * 16 + (l & 15);
    unsigned short hi[8], lo[8];
    #pragma unroll
    for (int j = 0; j < 8; ++j) {
        float v = Wh[(size_t)(k0 + j) * (4 * H_) + col];
        hi[j] = f2bf(v); lo[j] = f2bf(v - bf2f(hi[j]));
    }
    size_t base = ((((size_t)bx * 8 + w) * 4 + ct) * 4 + kf) * 2;
    WhF[(base + 0) * 64 + l] = *(uint4*)hi;
    WhF[(base + 1) * 64 + l] = *(uint4*)lo;
}

// ---------------------------------------------------------------------------
// hd-load + 48 MFMA + Rs2 scatter (the proven R9 inner block), from HT[TIDX].
// ---------------------------------------------------------------------------
#define HLOAD_MFMA(HT_BASE, TIDX)                                             \
    do {                                                                      \
        const unsigned* hTp_ = (HT_BASE) + (size_t)(TIDX) * HX16;             \
        unsigned hd[4][8];                                                    \
        _Pragma("unroll")                                                     \
        for (int kf = 0; kf < 4; ++kf) {                                      \
            const int k0 = w * 128 + kf * 32 + 8 * lhi;                       \
            _Pragma("unroll")                                                 \
            for (int j = 0; j < 8; ++j) {                                     \
                const unsigned* ap = hTp_ + (k0 + j) * 16 + l15;              \
                asm volatile("global_load_dword %0, %1, off sc0 sc1"          \
                             : "=&v"(hd[kf][j]) : "v"(ap));                   \
            }                                                                 \
        }                                                                     \
        asm volatile("s_waitcnt vmcnt(0)" ::: "memory");                      \
        __builtin_amdgcn_sched_barrier(0);                                    \
        f32x4 a0 = {0.f,0.f,0.f,0.f}, a1 = a0, a2 = a0, a3 = a0;              \
        _Pragma("unroll")                                                     \
        for (int kf = 0; kf < 4; ++kf) {                                      \
            unsigned short hh[8], hl[8];                                      \
            _Pragma("unroll")                                                 \
            for (int j = 0; j < 8; ++j) {                                     \
                unsigned d = hd[kf][j];                                       \
                hh[j] = (unsigned short)(d >> 16);                            \
                hl[j] = (unsigned short)(d & 0xFFFFu);                        \
            }                                                                 \
            short8 ah = *(short8*)hh, al = *(short8*)hl;                      \
            a0 = __builtin_amdgcn_mfma_f32_16x16x32_bf16(ah, Bhi[0][kf], a0, 0,0,0); \
            a0 = __builtin_amdgcn_mfma_f32_16x16x32_bf16(ah, Blo[0][kf], a0, 0,0,0); \
            a0 = __builtin_amdgcn_mfma_f32_16x16x32_bf16(al, Bhi[0][kf], a0, 0,0,0); \
            a1 = __builtin_amdgcn_mfma_f32_16x16x32_bf16(ah, Bhi[1][kf], a1, 0,0,0); \
            a1 = __builtin_amdgcn_mfma_f32_16x16x32_bf16(ah, Blo[1][kf], a1, 0,0,0); \
            a1 = __builtin_amdgcn_mfma_f32_16x16x32_bf16(al, Bhi[1][kf], a1, 0,0,0); \
            a2 = __builtin_amdgcn_mfma_f32_16x16x32_bf16(ah, Bhi[2][kf], a2, 0,0,0); \
            a2 = __builtin_amdgcn_mfma_f32_16x16x32_bf16(ah, Blo[2][kf], a2, 0,0,0); \
            a2 = __builtin_amdgcn_mfma_f32_16x16x32_bf16(al, Bhi[2][kf], a2, 0,0,0); \
            a3 = __builtin_amdgcn_mfma_f32_16x16x32_bf16(ah, Bhi[3][kf], a3, 0,0,0); \
            a3 = __builtin_amdgcn_mfma_f32_16x16x32_bf16(ah, Blo[3][kf], a3, 0,0,0); \
            a3 = __builtin_amdgcn_mfma_f32_16x16x32_bf16(al, Bhi[3][kf], a3, 0,0,0); \
        }                                                                     \
        _Pragma("unroll")                                                     \
        for (int r = 0; r < 4; ++r) {                                         \
            Rs2[r * 2048 + (0 * 8 + w) * 64 + l] = a0[r];                     \
            Rs2[r * 2048 + (1 * 8 + w) * 64 + l] = a1[r];                     \
            Rs2[r * 2048 + (2 * 8 + w) * 64 + l] = a2[r];                     \
            Rs2[r * 2048 + (3 * 8 + w) * 64 + l] = a3[r];                     \
        }                                                                     \
    } while (0)

// ---------------------------------------------------------------------------
// Fused 3-stage LSTM pipeline. 192 blocks x 512 threads (cooperative).
// role = blockIdx.x>>6: 0 = L0 recurrence, 1 = xz1 projection (h0@Wx1+b1),
// 2 = L1 recurrence. Stages chained by flag arrays (forward-only, no cycles):
//   flagsL0  : L0 self-barrier          (polled by 64 L0 blocks)
//   flagsL0b : L0 -> proj   handoff     (polled by 64 proj blocks)
//   flagsP   : proj -> L1   handoff     (polled by 64 L1 blocks)
//   flagsL1  : L1 self-barrier          (polled by 64 L1 blocks)
// Full (per-t) hT0/hT1/xz1 buffers -> no back-pressure anywhere.
// Each role's inner step is the proven R9/R12 structure.
// ---------------------------------------------------------------------------
__global__ __launch_bounds__(512, 1)
void lstm_fused_k(const float* __restrict__ xz0,   // [B*T][4H] (static, cached)
                  const uint4* __restrict__ WhF0,
                  const uint4* __restrict__ WxF1,
                  const uint4* __restrict__ WhF1,
                  const float* __restrict__ b1v,   // [4H]
                  float* __restrict__ xz1,         // [B*T][4H] (MALL)
                  unsigned* __restrict__ hT0,      // [T][H][16] packed
                  unsigned* __restrict__ hT1,      // [T][H][16] packed
                  float* __restrict__ h1seq,       // [B*T][H] (plain)
                  const int* __restrict__ tokens,
                  unsigned* __restrict__ flags)    // [256]
{
    __shared__ float Rs2[4 * 2048];

    unsigned* flagsL0  = flags;
    unsigned* flagsP   = flags + 64;
    unsigned* flagsL1  = flags + 128;
    unsigned* flagsL0b = flags + 192;

    const int tid  = threadIdx.x;
    const int role = blockIdx.x >> 6;
    const int bx   = blockIdx.x & 63;
    const int w    = tid >> 6;
    const int l    = tid & 63;
    const int l15  = l & 15, lhi = l >> 4;
    const int u    = bx * 16 + l15;
    const int bl   = lhi * 4 + w;                 // gate-lane batch (w<4)
    const size_t bt_base = (size_t)bl * T_;

    // one-time load of this role's weight fragments, pinned in registers
    short8 Bhi[4][4], Blo[4][4];
    {
        const uint4* wimg = (role == 0) ? WhF0 : (role == 1) ? WxF1 : WhF1;
        const uint4* p = wimg + (((size_t)bx * 8 + w) * 32) * 64;
        #pragma unroll
        for (int ct = 0; ct < 4; ++ct)
            #pragma unroll
            for (int kf = 0; kf < 4; ++kf) {
                uint4 hv = p[((ct * 4 + kf) * 2 + 0) * 64 + l];
                uint4 lv = p[((ct * 4 + kf) * 2 + 1) * 64 + l];
                Bhi[ct][kf] = *(short8*)&hv;
                Blo[ct][kf] = *(short8*)&lv;
            }
    }
    #pragma unroll
    for (int ct = 0; ct < 4; ++ct)
        #pragma unroll
        for (int kf = 0; kf < 4; ++kf) {
            asm volatile("" : "+v"(Bhi[ct][kf]));
            asm volatile("" : "+v"(Blo[ct][kf]));
        }

    if (role == 0) {
        // ----- L0 recurrence (proven R9 structure; full hT0 buffer) -----
        float c1 = 0.f, h1 = 0.f;
        for (int t = 0; t < T_; ++t) {
            float xzr[4];
            int tok = 0;
            if (w < 4) {
                size_t bt = bt_base + t;
                #pragma unroll
                for (int ct = 0; ct < 4; ++ct)
                    xzr[ct] = xz0[bt * 4096 + (size_t)ct * H_ + u];
                tok = tokens[bt];
            }
            if (t > 0) HLOAD_MFMA(hT0, t - 1);
            __syncthreads();

            if (w < 4) {
                float z[4];
                #pragma unroll
                for (int ct = 0; ct < 4; ++ct) {
                    float s = 0.f;
                    if (t > 0) {
                        #pragma unroll
                        for (int w2 = 0; w2 < 8; ++w2)
                            s += Rs2[w * 2048 + (ct * 8 + w2) * 64 + l];
                    }
                    z[ct] = s + xzr[ct];
                }
                float i_ = fsig(z[0]);
                float f_ = fsig(z[1]);
                float g_ = ftanh(z[2]);
                float o_ = fsig(z[3]);
                float c_new = f_ * c1 + i_ * g_;
                float h_new = o_ * ftanh(c_new);
                bool  m  = (tok != 0);
                float h2 = m ? h_new : h1;
                c1 = m ? c_new : c1;
                h1 = h2;
                unsigned short hh = f2bf(h2);
                unsigned short hl = f2bf(h2 - bf2f(hh));
                unsigned pack = ((unsigned)hh << 16) | hl;
                __hip_atomic_store(&hT0[(size_t)t * HX16 + u * 16 + bl], pack,
                                   __ATOMIC_RELAXED, __HIP_MEMORY_SCOPE_AGENT);
                asm volatile("s_waitcnt vmcnt(0)" ::: "memory");
            }
            __syncthreads();

            if (w == 0) {
                if (l == 0) {
                    __hip_atomic_store(&flagsL0[bx], (unsigned)(t + 1),
                                       __ATOMIC_RELAXED, __HIP_MEMORY_SCOPE_AGENT);
                    __hip_atomic_store(&flagsL0b[bx], (unsigned)(t + 1),
                                       __ATOMIC_RELAXED, __HIP_MEMORY_SCOPE_AGENT);
                }
                if (t + 1 < T_) {
                    const unsigned tgt = (unsigned)(t + 1);
                    while (true) {
                        unsigned fv = __hip_atomic_load(&flagsL0[l],
                            __ATOMIC_RELAXED, __HIP_MEMORY_SCOPE_AGENT);
                        if (__all(fv >= tgt)) break;
                        __builtin_amdgcn_s_sleep(1);
                    }
                }
            }
            __syncthreads();
        }
    } else if (role == 1) {
        // ----- xz1 projection: xz1(t) = h0(t) @ Wx1 + b1 -----
        float b1r[4];
        if (w < 4) {
            #pragma unroll
            for (int ct = 0; ct < 4; ++ct) b1r[ct] = b1v[ct * H_ + u];
        }
        for (int t = 0; t < T_; ++t) {
            if (w == 0) {
                const unsigned tgt = (unsigned)(t + 1);
                while (true) {
                    unsigned fv = __hip_atomic_load(&flagsL0b[l],
                        __ATOMIC_RELAXED, __HIP_MEMORY_SCOPE_AGENT);
                    if (__all(fv >= tgt)) break;
                    __builtin_amdgcn_s_sleep(1);
                }
            }
            __syncthreads();

            HLOAD_MFMA(hT0, t);
            __syncthreads();

            if (w < 4) {
                size_t bt = bt_base + t;
                #pragma unroll
                for (int ct = 0; ct < 4; ++ct) {
                    float s = 0.f;
                    #pragma unroll
                    for (int w2 = 0; w2 < 8; ++w2)
                        s += Rs2[w * 2048 + (ct * 8 + w2) * 64 + l];
                    float z = s + b1r[ct];
                    const float* ap = xz1 + bt * 4096 + (size_t)ct * H_ + u;
                    asm volatile("global_store_dword %0, %1, off sc0 sc1"
                                 :: "v"(ap), "v"(z) : "memory");
                }
                asm volatile("s_waitcnt vmcnt(0)" ::: "memory");
            }
            __syncthreads();
            if (tid == 0)
                __hip_atomic_store(&flagsP[bx], (unsigned)(t + 1),
                                   __ATOMIC_RELAXED, __HIP_MEMORY_SCOPE_AGENT);
        }
    } else {
        // ----- L1 recurrence (consumes xz1 via MALL) -----
        float c1 = 0.f, h1 = 0.f;
        for (int t = 0; t < T_; ++t) {
            if (w == 0) {
                const unsigned tp = (unsigned)(t + 1);
                while (true) {
                    unsigned f1 = __hip_atomic_load(&flagsP[l],
                        __ATOMIC_RELAXED, __HIP_MEMORY_SCOPE_AGENT);
                    unsigned f2 = __hip_atomic_load(&flagsL1[l],
                        __ATOMIC_RELAXED, __HIP_MEMORY_SCOPE_AGENT);
                    bool ok = (f1 >= tp) && (t == 0 || f2 >= (unsigned)t);
                    if (__all(ok)) break;
                    __builtin_amdgcn_s_sleep(1);
                }
            }
            __syncthreads();

            float xzr[4];
            int tok = 0;
            if (w < 4) {
                size_t bt = bt_base + t;
                #pragma unroll
                for (int ct = 0; ct < 4; ++ct) {
                    const float* ap = xz1 + bt * 4096 + (size_t)ct * H_ + u;
                    asm volatile("global_load_dword %0, %1, off sc0 sc1"
                                 : "=&v"(xzr[ct]) : "v"(ap));
                }
                tok = tokens[bt];
            }
            if (t > 0) HLOAD_MFMA(hT1, t - 1);
            __syncthreads();

            if (w < 4) {
                asm volatile("s_waitcnt vmcnt(0)" ::: "memory");  // xzr (t==0)
                __builtin_amdgcn_sched_barrier(0);
                float z[4];
                #pragma unroll
                for (int ct = 0; ct < 4; ++ct) {
                    float s = 0.f;
                    if (t > 0) {
                        #pragma unroll
                        for (int w2 = 0; w2 < 8; ++w2)
                            s += Rs2[w * 2048 + (ct * 8 + w2) * 64 + l];
                    }
                    z[ct] = s + xzr[ct];
                }
                float i_ = fsig(z[0]);
                float f_ = fsig(z[1]);
                float g_ = ftanh(z[2]);
                float o_ = fsig(z[3]);
                float c_new = f_ * c1 + i_ * g_;
                float h_new = o_ * ftanh(c_new);
                bool  m  = (tok != 0);
                float h2 = m ? h_new : h1;
                c1 = m ? c_new : c1;
                h1 = h2;
                size_t bt = bt_base + t;
                unsigned short hh = f2bf(h2);
                unsigned short hl = f2bf(h2 - bf2f(hh));
                unsigned pack = ((unsigned)hh << 16) | hl;
                __hip_atomic_store(&hT1[(size_t)t * HX16 + u * 16 + bl], pack,
                                   __ATOMIC_RELAXED, __HIP_MEMORY_SCOPE_AGENT);
                asm volatile("s_waitcnt vmcnt(0)" ::: "memory");
                h1seq[bt * H_ + u] = h2;          // off critical path
            }
            __syncthreads();
            if (tid == 0)
                __hip_atomic_store(&flagsL1[bx], (unsigned)(t + 1),
                                   __ATOMIC_RELAXED, __HIP_MEMORY_SCOPE_AGENT);
        }
    }
}

// ---------------------------------------------------------------------------
extern "C" void kernel_launch(void* const* d_in, const int* in_sizes, int n_in,
                              void* d_out, int out_size, void* d_ws, size_t ws_size,
                              hipStream_t stream)
{
    const int*   tokens = (const int*)d_in[0];
    const float* emb    = (const float*)d_in[1];
    const float* Wx0    = (const float*)d_in[2];
    const float* Wh0    = (const float*)d_in[3];
    const float* b0     = (const float*)d_in[4];
    const float* Wx1    = (const float*)d_in[5];
    const float* Wh1    = (const float*)d_in[6];
    const float* b1     = (const float*)d_in[7];
    const float* Wout   = (const float*)d_in[8];
    const float* bout   = (const float*)d_in[9];
    float* out = (float*)d_out;

    // d_ws: bf16 planes (~82.3 MB) + 256 flag words
    unsigned short* wsu = (unsigned short*)d_ws;
    const size_t BPL = (size_t)16000 * 1024;
    const size_t AP  = (size_t)4096 * 1024;
    unsigned short* Bh  = wsu;
    unsigned short* Bl  = wsu + BPL;
    unsigned short* Ahp = wsu + 2 * BPL;
    unsigned short* Alp = Ahp + AP;
    unsigned* flags = (unsigned*)(wsu + 2 * BPL + 2 * AP);   // 256 words

    // d_out head as fp32 scratch; all dead before final GEMM writes logits.
    float* f    = (float*)d_out;
    float* xz0  = f;                                  // 16.78M floats
    float* xz1  = xz0 + (size_t)4096 * 4096;          // 16.78M
    float* WhF0 = xz1 + (size_t)4096 * 4096;          // 4.19M each below
    float* WxF1 = WhF0 + (size_t)1024 * 4096;
    float* WhF1 = WxF1 + (size_t)1024 * 4096;
    unsigned* hT0 = (unsigned*)(WhF1 + (size_t)1024 * 4096);  // 4.19M u32
    unsigned* hT1 = hT0 + (size_t)T_ * HX16;                  // 4.19M u32
    float* h1s  = (float*)(hT1 + (size_t)T_ * HX16);          // 4.19M

    dim3 blk(256);

    // ---- layer 0 input projection ----
    gather_cvt_k<<<2048, blk, 0, stream>>>(tokens, emb, Ahp, Alp);
    twz_k<<<dim3(128, 16), blk, 0, stream>>>(Wx0, Bh, Bl, 512, 4096, 0);
    mgemm_k<0><<<dim3(32, 32), blk, 0, stream>>>(Ahp, Alp, Bh, Bl, b0, xz0,
                                                 nullptr, 512, 4096, 0);
    // ---- weight frag images + flag resets ----
    wprep_k<<<2048, blk, 0, stream>>>(Wh0, (uint4*)WhF0, flags, 64);
    wprep_k<<<2048, blk, 0, stream>>>(Wx1, (uint4*)WxF1, flags + 64, 64);
    wprep_k<<<2048, blk, 0, stream>>>(Wh1, (uint4*)WhF1, flags + 128, 128);
    // ---- fused 3-stage pipeline: L0 | xz1-proj | L1 ----
    {
        void* args[] = {(void*)&xz0, (void*)&WhF0, (void*)&WxF1, (void*)&WhF1,
                        (void*)&b1, (void*)&xz1, (void*)&hT0, (void*)&hT1,
                        (void*)&h1s, (void*)&tokens, (void*)&flags};
        hipLaunchCooperativeKernel((void*)lstm_fused_k, dim3(192), dim3(512),
                                   args, 0, stream);
    }
    // ---- vocab projection in two N-halves ----
    cvt_k<<<4096, blk, 0, stream>>>(h1s, Ahp, Alp);
    twz_k<<<dim3(500, 32), blk, 0, stream>>>(Wout, Bh, Bl, 1024, 32000, 0);
    mgemm_k<1><<<dim3(125, 32), blk, 0, stream>>>(Ahp, Alp, Bh, Bl, bout, out,
                                                  tokens, 1024, 32000, 0);
    twz_k<<<dim3(500, 32), blk, 0, stream>>>(Wout, Bh, Bl, 1024, 32000, 16000);
    mgemm_k<1><<<dim3(125, 32), blk, 0, stream>>>(Ahp, Alp, Bh, Bl, bout, out,
                                                  tokens, 1024, 32000, 16000);
}

// Round 16
// 2338.907 us; speedup vs baseline: 2.6363x; 1.0568x over previous
//
#include <hip/hip_runtime.h>

#define B_ 16
#define T_ 256
#define E_ 512
#define H_ 1024
#define V_ 32000
#define HX16 (H_ * 16)
#define SENT 0xFFFFFFFFu

typedef float f32x4 __attribute__((ext_vector_type(4)));
typedef short short8 __attribute__((ext_vector_type(8)));

typedef __attribute__((address_space(1))) const void gas_t;
typedef __attribute__((address_space(3))) void las_t;

__device__ __forceinline__ unsigned short f2bf(float x) {
    unsigned int u = __float_as_uint(x);
    u += 0x7FFF + ((u >> 16) & 1);            // RTNE
    return (unsigned short)(u >> 16);
}
__device__ __forceinline__ float bf2f(unsigned short b) {
    return __uint_as_float(((unsigned int)b) << 16);
}
__device__ __forceinline__ float fsig(float x) {
    return __fdividef(1.f, 1.f + __expf(-x));
}
__device__ __forceinline__ float ftanh(float x) {
    float xc = fminf(fmaxf(x, -15.f), 15.f);
    float e  = __expf(-2.f * xc);
    return __fdividef(1.f - e, 1.f + e);
}

// ---------------------------------------------------------------------------
__global__ __launch_bounds__(256)
void gather_cvt_k(const int* __restrict__ tokens, const float* __restrict__ emb,
                  unsigned short* __restrict__ Ah, unsigned short* __restrict__ Al)
{
    int i  = blockIdx.x * 256 + threadIdx.x;
    int bt = i >> 7;
    int e4 = i & 127;
    float4 v = ((const float4*)(emb + (size_t)tokens[bt] * E_))[e4];
    ushort4 h, l;
    h.x = f2bf(v.x); l.x = f2bf(v.x - bf2f(h.x));
    h.y = f2bf(v.y); l.y = f2bf(v.y - bf2f(h.y));
    h.z = f2bf(v.z); l.z = f2bf(v.z - bf2f(h.z));
    h.w = f2bf(v.w); l.w = f2bf(v.w - bf2f(h.w));
    ((ushort4*)Ah)[i] = h;
    ((ushort4*)Al)[i] = l;
}

// ---------------------------------------------------------------------------
__global__ __launch_bounds__(256)
void twz_k(const float* __restrict__ W, unsigned short* __restrict__ Bh,
           unsigned short* __restrict__ Bl, int Kd, int Nfull, int n0)
{
    __shared__ float tile[32][33];
    int t  = threadIdx.x;
    int tx = t & 31, ty = t >> 5;
    int nb = blockIdx.x * 32, kb = blockIdx.y * 32;
    #pragma unroll
    for (int i = 0; i < 4; ++i)
        tile[ty + i * 8][tx] = W[(size_t)(kb + ty + i * 8) * Nfull + n0 + nb + tx];
    __syncthreads();
    #pragma unroll
    for (int i = 0; i < 4; ++i) {
        float v = tile[tx][ty + i * 8];
        unsigned short h = f2bf(v), l = f2bf(v - bf2f(h));
        size_t o = (size_t)(nb + ty + i * 8) * Kd + kb + tx;
        Bh[o] = h; Bl[o] = l;
    }
}

// ---------------------------------------------------------------------------
// Split-bf16 3-pass MFMA GEMM (round-5-verified core) + bijective XCD swizzle.
// ---------------------------------------------------------------------------
template<int DO_MASK>
__global__ __launch_bounds__(256)
void mgemm_k(const unsigned short* __restrict__ Ah, const unsigned short* __restrict__ Al,
             const unsigned short* __restrict__ Bh, const unsigned short* __restrict__ Bl,
             const float* __restrict__ bias, float* __restrict__ C,
             const int* __restrict__ tokens, int K, int ldc, int n0)
{
    __shared__ unsigned short LDSS[4][128 * 64];

    const int tid  = threadIdx.x;
    const int nwg = gridDim.x * gridDim.y;
    int lin = blockIdx.y * gridDim.x + blockIdx.x;
    lin = (lin & 7) * (nwg >> 3) + (lin >> 3);
    const int bm   = (lin / gridDim.x) * 128;
    const int bn   = (lin % gridDim.x) * 128;
    const int w    = tid >> 6, lane = tid & 63;
    const int wm   = (w >> 1) * 64, wn = (w & 1) * 64;
    const int l15  = lane & 15, lhi = lane >> 4;

    const unsigned short* gp = (w == 0) ? Ah : (w == 1) ? Al : (w == 2) ? Bh : Bl;
    const int rb = (w < 2) ? bm : bn;
    const int srow = lane >> 3;
    const int scol = (lane & 7) ^ srow;
    unsigned short* lbase = &LDSS[w][0];

    f32x4 acc[4][4];
    #pragma unroll
    for (int mi = 0; mi < 4; ++mi)
        #pragma unroll
        for (int ni = 0; ni < 4; ++ni) {
            f32x4 z = {0.f, 0.f, 0.f, 0.f};
            acc[mi][ni] = z;
        }

    for (int kt = 0; kt < K; kt += 64) {
        #pragma unroll
        for (int c = 0; c < 16; ++c) {
            const unsigned short* src =
                gp + (size_t)(rb + c * 8 + srow) * K + kt + scol * 8;
            __builtin_amdgcn_global_load_lds((gas_t*)src,
                                             (las_t*)(lbase + c * 512), 16, 0, 0);
        }
        __syncthreads();
        #pragma unroll
        for (int ks = 0; ks < 2; ++ks) {
            short8 ah[4], al[4], bh[4], bl[4];
            const int s = ks * 4 + lhi;
            #pragma unroll
            for (int mi = 0; mi < 4; ++mi) {
                int m = wm + mi * 16 + l15;
                int off = m * 64 + ((s ^ (m & 7)) * 8);
                ah[mi] = *(const short8*)(&LDSS[0][off]);
                al[mi] = *(const short8*)(&LDSS[1][off]);
            }
            #pragma unroll
            for (int ni = 0; ni < 4; ++ni) {
                int n = wn + ni * 16 + l15;
                int off = n * 64 + ((s ^ (n & 7)) * 8);
                bh[ni] = *(const short8*)(&LDSS[2][off]);
                bl[ni] = *(const short8*)(&LDSS[3][off]);
            }
            #pragma unroll
            for (int mi = 0; mi < 4; ++mi)
                #pragma unroll
                for (int ni = 0; ni < 4; ++ni) {
                    acc[mi][ni] = __builtin_amdgcn_mfma_f32_16x16x32_bf16(
                        ah[mi], bh[ni], acc[mi][ni], 0, 0, 0);
                    acc[mi][ni] = __builtin_amdgcn_mfma_f32_16x16x32_bf16(
                        ah[mi], bl[ni], acc[mi][ni], 0, 0, 0);
                    acc[mi][ni] = __builtin_amdgcn_mfma_f32_16x16x32_bf16(
                        al[mi], bh[ni], acc[mi][ni], 0, 0, 0);
                }
        }
        __syncthreads();
    }

    #pragma unroll
    for (int mi = 0; mi < 4; ++mi) {
        #pragma unroll
        for (int r = 0; r < 4; ++r) {
            int row = bm + wm + mi * 16 + lhi * 4 + r;
            bool msk = true;
            if (DO_MASK) msk = (tokens[row] != 0);
            #pragma unroll
            for (int ni = 0; ni < 4; ++ni) {
                int col = bn + wn + ni * 16 + l15;
                float v = acc[mi][ni][r] + bias[n0 + col];
                if (DO_MASK && !msk) v = ((n0 + col) == 0) ? 1.f : 0.f;
                C[(size_t)row * ldc + n0 + col] = v;
            }
        }
    }
}

// ---------------------------------------------------------------------------
// W [1024][4096] fp32 -> register-fragment image (bf16 hi/lo B-frags).
// ---------------------------------------------------------------------------
__global__ __launch_bounds__(256)
void wprep_k(const float* __restrict__ Wh, uint4* __restrict__ WhF)
{
    int flat = blockIdx.x * 256 + threadIdx.x;
    int l  = flat & 63;
    int kf = (flat >> 6) & 3;
    int ct = (flat >> 8) & 3;
    int w  = (flat >> 10) & 7;
    int bx = flat >> 13;
    int k0  = w * 128 + kf * 32 + 8 * (l >> 4);
    int col = ct * H_ + bx * 16 + (l & 15);
    unsigned short hi[8], lo[8];
    #pragma unroll
    for (int j = 0; j < 8; ++j) {
        float v = Wh[(size_t)(k0 + j) * (4 * H_) + col];
        hi[j] = f2bf(v); lo[j] = f2bf(v - bf2f(hi[j]));
    }
    size_t base = ((((size_t)bx * 8 + w) * 4 + ct) * 4 + kf) * 2;
    WhF[(base + 0) * 64 + l] = *(uint4*)hi;
    WhF[(base + 1) * 64 + l] = *(uint4*)lo;
}

// ---------------------------------------------------------------------------
// Sentinel fill: 0xFFFFFFFF everywhere (covers xz1 + hT0 + hT1 contiguous).
// ---------------------------------------------------------------------------
__global__ __launch_bounds__(256)
void sfill_k(uint4* __restrict__ p, unsigned n4)
{
    uint4 s = {SENT, SENT, SENT, SENT};
    for (size_t i = (size_t)blockIdx.x * 256 + threadIdx.x; i < n4;
         i += (size_t)gridDim.x * 256)
        p[i] = s;
}

// ---------------------------------------------------------------------------
// MFMA + Rs2 scatter from already-loaded hd[4][8].
// ---------------------------------------------------------------------------
#define MFMA_FROM_HD()                                                        \
    do {                                                                      \
        f32x4 a0 = {0.f,0.f,0.f,0.f}, a1 = a0, a2 = a0, a3 = a0;              \
        _Pragma("unroll")                                                     \
        for (int kf = 0; kf < 4; ++kf) {                                      \
            unsigned short hh[8], hl[8];                                      \
            _Pragma("unroll")                                                 \
            for (int j = 0; j < 8; ++j) {                                     \
                unsigned d = hd[kf][j];                                       \
                hh[j] = (unsigned short)(d >> 16);                            \
                hl[j] = (unsigned short)(d & 0xFFFFu);                        \
            }                                                                 \
            short8 ah = *(short8*)hh, al = *(short8*)hl;                      \
            a0 = __builtin_amdgcn_mfma_f32_16x16x32_bf16(ah, Bhi[0][kf], a0, 0,0,0); \
            a0 = __builtin_amdgcn_mfma_f32_16x16x32_bf16(ah, Blo[0][kf], a0, 0,0,0); \
            a0 = __builtin_amdgcn_mfma_f32_16x16x32_bf16(al, Bhi[0][kf], a0, 0,0,0); \
            a1 = __builtin_amdgcn_mfma_f32_16x16x32_bf16(ah, Bhi[1][kf], a1, 0,0,0); \
            a1 = __builtin_amdgcn_mfma_f32_16x16x32_bf16(ah, Blo[1][kf], a1, 0,0,0); \
            a1 = __builtin_amdgcn_mfma_f32_16x16x32_bf16(al, Bhi[1][kf], a1, 0,0,0); \
            a2 = __builtin_amdgcn_mfma_f32_16x16x32_bf16(ah, Bhi[2][kf], a2, 0,0,0); \
            a2 = __builtin_amdgcn_mfma_f32_16x16x32_bf16(ah, Blo[2][kf], a2, 0,0,0); \
            a2 = __builtin_amdgcn_mfma_f32_16x16x32_bf16(al, Bhi[2][kf], a2, 0,0,0); \
            a3 = __builtin_amdgcn_mfma_f32_16x16x32_bf16(ah, Bhi[3][kf], a3, 0,0,0); \
            a3 = __builtin_amdgcn_mfma_f32_16x16x32_bf16(ah, Blo[3][kf], a3, 0,0,0); \
            a3 = __builtin_amdgcn_mfma_f32_16x16x32_bf16(al, Bhi[3][kf], a3, 0,0,0); \
        }                                                                     \
        _Pragma("unroll")                                                     \
        for (int r = 0; r < 4; ++r) {                                         \
            Rs2[r * 2048 + (0 * 8 + w) * 64 + l] = a0[r];                     \
            Rs2[r * 2048 + (1 * 8 + w) * 64 + l] = a1[r];                     \
            Rs2[r * 2048 + (2 * 8 + w) * 64 + l] = a2[r];                     \
            Rs2[r * 2048 + (3 * 8 + w) * 64 + l] = a3[r];                     \
        }                                                                     \
    } while (0)

// issue this wave's 32 h loads for HT[TIDX]
#define ISSUE_H(HT_BASE, TIDX)                                                \
    do {                                                                      \
        const unsigned* hTp_ = (HT_BASE) + (size_t)(TIDX) * HX16;             \
        _Pragma("unroll")                                                     \
        for (int kf = 0; kf < 4; ++kf) {                                      \
            const int k0 = w * 128 + kf * 32 + 8 * lhi;                       \
            _Pragma("unroll")                                                 \
            for (int j = 0; j < 8; ++j) {                                     \
                const unsigned* ap = hTp_ + (k0 + j) * 16 + l15;              \
                asm volatile("global_load_dword %0, %1, off sc0 sc1"          \
                             : "=&v"(hd[kf][j]) : "v"(ap));                   \
            }                                                                 \
        }                                                                     \
    } while (0)

#define HD_BAD(BADV)                                                          \
    do {                                                                      \
        _Pragma("unroll")                                                     \
        for (int kf = 0; kf < 4; ++kf)                                        \
            _Pragma("unroll")                                                 \
            for (int j = 0; j < 8; ++j)                                       \
                (BADV) |= (hd[kf][j] == SENT);                                \
    } while (0)

// ---------------------------------------------------------------------------
// Fused 3-stage LSTM pipeline, round-16: FLAG-FREE sentinel synchronization.
// Producers just store (packed bf16 pairs / xz1 floats, never 0xFFFFFFFF);
// consumers poll their own data for the sentinel with s_sleep backoff.
// Per-step chain drops from ~3 MALL RTTs (store-drain + flag + load) to
// ~1.5 (store propagate || consumer load). No drains, no flags, no wave-0
// relay. Full per-t hT0/hT1/xz1 buffers -> no back-pressure, no deadlock.
// L1 additionally stores Ahp/Alp (bf16 splits of h1) directly -> cvt_k gone.
// ---------------------------------------------------------------------------
__global__ __launch_bounds__(512, 1)
void lstm_fused_k(const float* __restrict__ xz0,
                  const uint4* __restrict__ WhF0,
                  const uint4* __restrict__ WxF1,
                  const uint4* __restrict__ WhF1,
                  const float* __restrict__ b1v,
                  float* __restrict__ xz1,
                  unsigned* __restrict__ hT0,      // [T][H][16] packed
                  unsigned* __restrict__ hT1,      // [T][H][16] packed
                  unsigned short* __restrict__ Ahp,
                  unsigned short* __restrict__ Alp,
                  const int* __restrict__ tokens)
{
    __shared__ float Rs2[4 * 2048];

    const int tid  = threadIdx.x;
    const int role = blockIdx.x >> 6;
    const int bx   = blockIdx.x & 63;
    const int w    = tid >> 6;
    const int l    = tid & 63;
    const int l15  = l & 15, lhi = l >> 4;
    const int u    = bx * 16 + l15;
    const int bl   = lhi * 4 + w;                 // gate-lane batch (w<4)
    const size_t bt_base = (size_t)bl * T_;

    // one-time load of this role's weight fragments, pinned in registers
    short8 Bhi[4][4], Blo[4][4];
    {
        const uint4* wimg = (role == 0) ? WhF0 : (role == 1) ? WxF1 : WhF1;
        const uint4* p = wimg + (((size_t)bx * 8 + w) * 32) * 64;
        #pragma unroll
        for (int ct = 0; ct < 4; ++ct)
            #pragma unroll
            for (int kf = 0; kf < 4; ++kf) {
                uint4 hv = p[((ct * 4 + kf) * 2 + 0) * 64 + l];
                uint4 lv = p[((ct * 4 + kf) * 2 + 1) * 64 + l];
                Bhi[ct][kf] = *(short8*)&hv;
                Blo[ct][kf] = *(short8*)&lv;
            }
    }
    #pragma unroll
    for (int ct = 0; ct < 4; ++ct)
        #pragma unroll
        for (int kf = 0; kf < 4; ++kf) {
            asm volatile("" : "+v"(Bhi[ct][kf]));
            asm volatile("" : "+v"(Blo[ct][kf]));
        }

    if (role == 0) {
        // ----- L0 recurrence -----
        float c1 = 0.f, h1v = 0.f;
        for (int t = 0; t < T_; ++t) {
            float xzr[4];
            int tok = 0;
            if (w < 4) {
                size_t bt = bt_base + t;
                #pragma unroll
                for (int ct = 0; ct < 4; ++ct)
                    xzr[ct] = xz0[bt * 4096 + (size_t)ct * H_ + u];
                tok = tokens[bt];
            }
            if (t > 0) {
                unsigned hd[4][8];
                while (true) {
                    ISSUE_H(hT0, t - 1);
                    asm volatile("s_waitcnt vmcnt(0)" ::: "memory");
                    __builtin_amdgcn_sched_barrier(0);
                    bool bad = false;
                    HD_BAD(bad);
                    if (!__any(bad)) break;
                    __builtin_amdgcn_s_sleep(2);
                }
                MFMA_FROM_HD();
            }
            __syncthreads();

            if (w < 4) {
                float z[4];
                #pragma unroll
                for (int ct = 0; ct < 4; ++ct) {
                    float s = 0.f;
                    if (t > 0) {
                        #pragma unroll
                        for (int w2 = 0; w2 < 8; ++w2)
                            s += Rs2[w * 2048 + (ct * 8 + w2) * 64 + l];
                    }
                    z[ct] = s + xzr[ct];
                }
                float i_ = fsig(z[0]);
                float f_ = fsig(z[1]);
                float g_ = ftanh(z[2]);
                float o_ = fsig(z[3]);
                float c_new = f_ * c1 + i_ * g_;
                float h_new = o_ * ftanh(c_new);
                bool  m  = (tok != 0);
                float h2 = m ? h_new : h1v;
                c1  = m ? c_new : c1;
                h1v = h2;
                unsigned short hh = f2bf(h2);
                unsigned short hl = f2bf(h2 - bf2f(hh));
                unsigned pack = ((unsigned)hh << 16) | hl;
                __hip_atomic_store(&hT0[(size_t)t * HX16 + u * 16 + bl], pack,
                                   __ATOMIC_RELAXED, __HIP_MEMORY_SCOPE_AGENT);
            }
            __syncthreads();
        }
    } else if (role == 1) {
        // ----- xz1 projection: xz1(t) = h0(t) @ Wx1 + b1 -----
        float b1r[4];
        if (w < 4) {
            #pragma unroll
            for (int ct = 0; ct < 4; ++ct) b1r[ct] = b1v[ct * H_ + u];
        }
        for (int t = 0; t < T_; ++t) {
            {
                unsigned hd[4][8];
                while (true) {
                    ISSUE_H(hT0, t);
                    asm volatile("s_waitcnt vmcnt(0)" ::: "memory");
                    __builtin_amdgcn_sched_barrier(0);
                    bool bad = false;
                    HD_BAD(bad);
                    if (!__any(bad)) break;
                    __builtin_amdgcn_s_sleep(2);
                }
                MFMA_FROM_HD();
            }
            __syncthreads();

            if (w < 4) {
                size_t bt = bt_base + t;
                #pragma unroll
                for (int ct = 0; ct < 4; ++ct) {
                    float s = 0.f;
                    #pragma unroll
                    for (int w2 = 0; w2 < 8; ++w2)
                        s += Rs2[w * 2048 + (ct * 8 + w2) * 64 + l];
                    float z = s + b1r[ct];
                    const float* ap = xz1 + bt * 4096 + (size_t)ct * H_ + u;
                    asm volatile("global_store_dword %0, %1, off sc0 sc1"
                                 :: "v"(ap), "v"(z) : "memory");
                }
            }
            __syncthreads();
        }
    } else {
        // ----- L1 recurrence (consumes xz1 + own hT1, both via sentinel) ---
        float c1 = 0.f, h1v = 0.f;
        for (int t = 0; t < T_; ++t) {
            unsigned hd[4][8];
            unsigned xzu[4];
            int tok = 0;
            size_t bt = bt_base + t;
            if (w < 4) tok = tokens[bt];
            while (true) {
                if (w < 4) {
                    #pragma unroll
                    for (int ct = 0; ct < 4; ++ct) {
                        const float* ap = xz1 + bt * 4096 + (size_t)ct * H_ + u;
                        asm volatile("global_load_dword %0, %1, off sc0 sc1"
                                     : "=&v"(xzu[ct]) : "v"(ap));
                    }
                }
                if (t > 0) ISSUE_H(hT1, t - 1);
                asm volatile("s_waitcnt vmcnt(0)" ::: "memory");
                __builtin_amdgcn_sched_barrier(0);
                bool bad = false;
                if (w < 4) {
                    #pragma unroll
                    for (int ct = 0; ct < 4; ++ct) bad |= (xzu[ct] == SENT);
                }
                if (t > 0) HD_BAD(bad);
                if (!__any(bad)) break;
                __builtin_amdgcn_s_sleep(2);
            }
            if (t > 0) MFMA_FROM_HD();
            __syncthreads();

            if (w < 4) {
                float z[4];
                #pragma unroll
                for (int ct = 0; ct < 4; ++ct) {
                    float s = 0.f;
                    if (t > 0) {
                        #pragma unroll
                        for (int w2 = 0; w2 < 8; ++w2)
                            s += Rs2[w * 2048 + (ct * 8 + w2) * 64 + l];
                    }
                    z[ct] = s + __uint_as_float(xzu[ct]);
                }
                float i_ = fsig(z[0]);
                float f_ = fsig(z[1]);
                float g_ = ftanh(z[2]);
                float o_ = fsig(z[3]);
                float c_new = f_ * c1 + i_ * g_;
                float h_new = o_ * ftanh(c_new);
                bool  m  = (tok != 0);
                float h2 = m ? h_new : h1v;
                c1  = m ? c_new : c1;
                h1v = h2;
                unsigned short hh = f2bf(h2);
                unsigned short hl = f2bf(h2 - bf2f(hh));
                unsigned pack = ((unsigned)hh << 16) | hl;
                __hip_atomic_store(&hT1[(size_t)t * HX16 + u * 16 + bl], pack,
                                   __ATOMIC_RELAXED, __HIP_MEMORY_SCOPE_AGENT);
                // bf16 split planes for the vocab GEMM (plain cached stores)
                Ahp[bt * (size_t)H_ + u] = hh;
                Alp[bt * (size_t)H_ + u] = hl;
            }
            __syncthreads();
        }
    }
}

// ---------------------------------------------------------------------------
extern "C" void kernel_launch(void* const* d_in, const int* in_sizes, int n_in,
                              void* d_out, int out_size, void* d_ws, size_t ws_size,
                              hipStream_t stream)
{
    const int*   tokens = (const int*)d_in[0];
    const float* emb    = (const float*)d_in[1];
    const float* Wx0    = (const float*)d_in[2];
    const float* Wh0    = (const float*)d_in[3];
    const float* b0     = (const float*)d_in[4];
    const float* Wx1    = (const float*)d_in[5];
    const float* Wh1    = (const float*)d_in[6];
    const float* b1     = (const float*)d_in[7];
    const float* Wout   = (const float*)d_in[8];
    const float* bout   = (const float*)d_in[9];
    float* out = (float*)d_out;

    // d_ws: bf16 planes (~82.3 MB)
    unsigned short* wsu = (unsigned short*)d_ws;
    const size_t BPL = (size_t)16000 * 1024;
    const size_t AP  = (size_t)4096 * 1024;
    unsigned short* Bh  = wsu;
    unsigned short* Bl  = wsu + BPL;
    unsigned short* Ahp = wsu + 2 * BPL;
    unsigned short* Alp = Ahp + AP;

    // d_out head as fp32 scratch (54.6M floats < 131M); dead before final GEMM.
    float* f    = (float*)d_out;
    float* xz0  = f;                                  // 16.78M floats
    float* WhF0 = xz0 + (size_t)4096 * 4096;          // 4.19M
    float* WxF1 = WhF0 + (size_t)1024 * 4096;         // 4.19M
    float* WhF1 = WxF1 + (size_t)1024 * 4096;         // 4.19M
    float* xz1  = WhF1 + (size_t)1024 * 4096;         // 16.78M
    unsigned* hT0 = (unsigned*)(xz1 + (size_t)4096 * 4096);   // 4.19M u32
    unsigned* hT1 = hT0 + (size_t)T_ * HX16;                  // 4.19M u32
    // xz1 + hT0 + hT1 are contiguous: 25,165,824 u32 = 6,291,456 uint4

    dim3 blk(256);

    // ---- layer 0 input projection ----
    gather_cvt_k<<<2048, blk, 0, stream>>>(tokens, emb, Ahp, Alp);
    twz_k<<<dim3(128, 16), blk, 0, stream>>>(Wx0, Bh, Bl, 512, 4096, 0);
    mgemm_k<0><<<dim3(32, 32), blk, 0, stream>>>(Ahp, Alp, Bh, Bl, b0, xz0,
                                                 nullptr, 512, 4096, 0);
    // ---- weight frag images + sentinel fill ----
    wprep_k<<<2048, blk, 0, stream>>>(Wh0, (uint4*)WhF0);
    wprep_k<<<2048, blk, 0, stream>>>(Wx1, (uint4*)WxF1);
    wprep_k<<<2048, blk, 0, stream>>>(Wh1, (uint4*)WhF1);
    sfill_k<<<4096, blk, 0, stream>>>((uint4*)xz1, 6291456u);
    // ---- fused 3-stage pipeline: L0 | xz1-proj | L1 (flag-free) ----
    {
        void* args[] = {(void*)&xz0, (void*)&WhF0, (void*)&WxF1, (void*)&WhF1,
                        (void*)&b1, (void*)&xz1, (void*)&hT0, (void*)&hT1,
                        (void*)&Ahp, (void*)&Alp, (void*)&tokens};
        hipLaunchCooperativeKernel((void*)lstm_fused_k, dim3(192), dim3(512),
                                   args, 0, stream);
    }
    // ---- vocab projection in two N-halves (Ahp/Alp written by L1 role) ----
    twz_k<<<dim3(500, 32), blk, 0, stream>>>(Wout, Bh, Bl, 1024, 32000, 0);
    mgemm_k<1><<<dim3(125, 32), blk, 0, stream>>>(Ahp, Alp, Bh, Bl, bout, out,
                                                  tokens, 1024, 32000, 0);
    twz_k<<<dim3(500, 32), blk, 0, stream>>>(Wout, Bh, Bl, 1024, 32000, 16000);
    mgemm_k<1><<<dim3(125, 32), blk, 0, stream>>>(Ahp, Alp, Bh, Bl, bout, out,
                                                  tokens, 1024, 32000, 16000);
}